// Round 11
// baseline (347.084 us; speedup 1.0000x reference)
//
#include <hip/hip_runtime.h>
#include <hip/hip_cooperative_groups.h>

#define KTOP 1000
#define NB 1024
#define CAP 2048
#define PCAP 1024
#define RBLK 8             // blocks per image
#define REL1 0.1f
#define REL2 0.05f

typedef unsigned long long u64;
typedef unsigned int u32;
namespace cg = cooperative_groups;

__device__ __forceinline__ const float* pick_scores(const void* A, const void* B, int flag) {
    return flag ? (const float*)B : (const float*)A;   // flag=1 -> A is classes
}
__device__ __forceinline__ const int* pick_classes(const void* A, const void* B, int flag) {
    return flag ? (const int*)A : (const int*)B;
}

__device__ __forceinline__ int bucket_of(float v) {
    int bu = (int)(v * (float)NB);           // *1024 exact (pow2) -> monotone
    return bu < 0 ? 0 : (bu > NB - 1 ? NB - 1 : bu);
}

__global__ __launch_bounds__(1024) void fused_kernel(const void* __restrict__ pA,
                                                     const void* __restrict__ pB,
                                                     const float4* __restrict__ boxes, int N,
                                                     int* __restrict__ phist,     // [B][RBLK][NB]
                                                     int* __restrict__ cutoff,    // [B]
                                                     int* __restrict__ cnt,       // [B]
                                                     u64* __restrict__ cand64,    // [B][CAP]
                                                     float* __restrict__ out, int B) {
    __shared__ int hh[NB];            //  4096 (P1 block hist; P2 summed hist)
    __shared__ int csum[256];         //  1024
    __shared__ u64 uni[CAP];          // 16384: P4 key[] -> myPos/pairs/sorted (disjoint lifetimes)
    __shared__ float4 sbox[KTOP];     // 16000
    __shared__ float sarea[KTOP];     //  4000
    __shared__ float sscore[KTOP];    //  4000
    __shared__ int scls[KTOP];        //  4000
    __shared__ short items[KTOP];     //  2000
    __shared__ int clsCnt[128];
    __shared__ int clsStart[128];
    __shared__ u64 keepw[16];
    __shared__ int firstIdx[128];
    __shared__ int wtot[16];
    __shared__ int wsum[16];
    __shared__ int ldsf, npair, sbase;

    cg::grid_group grid = cg::this_grid();

    u64* key    = uni;
    int* myPos  = (int*)uni;
    u32* pairs  = (u32*)uni;
    u32* sorted = ((u32*)uni) + PCAP;

    int b = blockIdx.x / RBLK;
    int r = blockIdx.x % RBLK;
    int tid = threadIdx.x;
    int lane = tid & 63;
    int wid = tid >> 6;

    // ---- input-ID flag (scores vs classes), per block ----
    if (tid == 0) { ldsf = 0; npair = 0; }
    __syncthreads();
    if (tid < 256) {
        u32 v = ((const u32*)pA)[tid];
        u64 big = __ballot(v >= 256u);
        if ((tid & 63) == 0 && big) atomicOr(&ldsf, 1);
    }
    __syncthreads();
    int flag = ldsf ? 0 : 1;
    const float* s = pick_scores(pA, pB, flag) + (size_t)b * N;
    const float4* s4 = (const float4*)s;
    int N4 = N >> 2;

    // ================= P1: partial histogram (this block's slice) =================
    hh[tid] = 0;
    if (tid < 128) { clsCnt[tid] = 0; firstIdx[tid] = 0x7fffffff; }
    __syncthreads();
    for (int i = r * 1024 + tid; i < N4; i += RBLK * 1024) {
        float4 v = s4[i];
        atomicAdd(&hh[bucket_of(v.x)], 1);
        atomicAdd(&hh[bucket_of(v.y)], 1);
        atomicAdd(&hh[bucket_of(v.z)], 1);
        atomicAdd(&hh[bucket_of(v.w)], 1);
    }
    for (int i = N4 * 4 + r * 1024 + tid; i < N; i += RBLK * 1024)
        atomicAdd(&hh[bucket_of(s[i])], 1);
    __syncthreads();
    phist[((size_t)b * RBLK + r) * NB + tid] = hh[tid];
    __threadfence();
    grid.sync();

    // ================= P2: cutoff per image (blocks with r==0) =================
    if (r == 0) {
        const int* src = phist + (size_t)b * RBLK * NB;
        int acc = 0;
#pragma unroll
        for (int k = 0; k < RBLK; ++k) acc += src[k * NB + tid];
        hh[tid] = acc;
        __syncthreads();
        if (tid < 256) {
            int base = NB - 1 - tid * (NB / 256);
            int a2 = 0;
#pragma unroll
            for (int k = 0; k < NB / 256; ++k) a2 += hh[base - k];
            csum[tid] = a2;
        }
        __syncthreads();
        if (tid == 0) {          // bucket of the KTOP-th largest score (verbatim logic)
            int cum = 0, cut = 0;
            for (int u = 0; u < 256; ++u) {
                if (cum + csum[u] >= KTOP) {
                    for (int k = 0; k < NB / 256; ++k) {
                        cum += hh[NB - 1 - u * (NB / 256) - k];
                        if (cum >= KTOP) { cut = NB - 1 - u * (NB / 256) - k; break; }
                    }
                    break;
                }
                cum += csum[u];
            }
            cutoff[b] = cut;
            cnt[b] = 0;
        }
    }
    __threadfence();
    grid.sync();

    // ================= P3: collect candidates (all blocks) =================
    {
        int cut = cutoff[b];
        int nloc = 0;
        for (int i = r * 1024 + tid; i < N4; i += RBLK * 1024) {
            float4 v = s4[i];
            nloc += (bucket_of(v.x) >= cut) + (bucket_of(v.y) >= cut) +
                    (bucket_of(v.z) >= cut) + (bucket_of(v.w) >= cut);
        }
        for (int i = N4 * 4 + r * 1024 + tid; i < N; i += RBLK * 1024)
            nloc += (bucket_of(s[i]) >= cut);

        // block prefix: wave shfl-scan + wave-total scan
        int inc = nloc;
        for (int d = 1; d < 64; d <<= 1) {
            int y = __shfl_up(inc, d);
            if (lane >= d) inc += y;
        }
        if (lane == 63) wsum[wid] = inc;
        __syncthreads();
        if (tid == 0) {
            int a = 0;
            for (int k = 0; k < 16; ++k) { int c = wsum[k]; wsum[k] = a; a += c; }
            sbase = a ? atomicAdd(&cnt[b], a) : 0;
        }
        __syncthreads();
        int pos = sbase + wsum[wid] + inc - nloc;
        u64* cb = cand64 + (size_t)b * CAP;
        for (int i = r * 1024 + tid; i < N4; i += RBLK * 1024) {   // L1/L2-hot re-read
            float4 v = s4[i];
            float vv[4] = {v.x, v.y, v.z, v.w};
#pragma unroll
            for (int k = 0; k < 4; ++k) {
                if (bucket_of(vv[k]) >= cut) {
                    if (pos < CAP)
                        cb[pos] = ((u64)__float_as_uint(vv[k]) << 32) | (u32)(~(u32)(i * 4 + k));
                    ++pos;
                }
            }
        }
        for (int i = N4 * 4 + r * 1024 + tid; i < N; i += RBLK * 1024) {
            float v = s[i];
            if (bucket_of(v) >= cut) {
                if (pos < CAP)
                    cb[pos] = ((u64)__float_as_uint(v) << 32) | (u32)(~(u32)i);
                ++pos;
            }
        }
    }
    __threadfence();
    grid.sync();

    // ================= P4: rank + NMS + thresholds + output (r==0 blocks) =================
    if (r != 0) return;

    int M = cnt[b]; if (M > CAP) M = CAP;
    for (int e = tid; e < M; e += 1024) key[e] = cand64[(size_t)b * CAP + e];
    __syncthreads();

    // rank-by-count: exact top_k order (score desc, ties -> lower idx); keys unique
    {
        int c0 = tid, c1 = tid + 1024;
        u64 kc0 = (c0 < M) ? key[c0] : 0;
        u64 kc1 = (c1 < M) ? key[c1] : 0;
        int r0 = 0, r1 = 0;
        for (int j = 0; j < M; ++j) {
            u64 kj = key[j];               // LDS broadcast
            r0 += (kj > kc0);
            r1 += (kj > kc1);
        }
        const int* classes = pick_classes(pA, pB, flag);
        if (c0 < M && r0 < KTOP) {
            int idx = (int)(~(u32)kc0);
            sscore[r0] = __uint_as_float((u32)(kc0 >> 32));
            scls[r0] = classes[(size_t)b * N + idx];
            sbox[r0] = boxes[(size_t)b * N + idx];
        }
        if (c1 < M && r1 < KTOP) {
            int idx = (int)(~(u32)kc1);
            sscore[r1] = __uint_as_float((u32)(kc1 >> 32));
            scls[r1] = classes[(size_t)b * N + idx];
            sbox[r1] = boxes[(size_t)b * N + idx];
        }
    }
    __syncthreads();   // key[] dead; uni reused

    // class bucketing
    if (tid < KTOP) {
        float4 bx = sbox[tid];
        sarea[tid] = (bx.z - bx.x) * (bx.w - bx.y);
        myPos[tid] = atomicAdd(&clsCnt[scls[tid] & 127], 1);
    }
    __syncthreads();
    if (tid == 0) {
        int acc = 0;
        for (int c = 0; c < 128; ++c) { clsStart[c] = acc; acc += clsCnt[c]; }
    }
    __syncthreads();
    if (tid < KTOP) items[clsStart[scls[tid] & 127] + myPos[tid]] = (short)tid;
    __syncthreads();   // myPos dead

    // pair finding within class buckets (avg ~12.5 entries)
    if (tid < KTOP) {
        int i = tid;
        float4 bi = sbox[i];
        float ai = sarea[i];
        int ci = scls[i];
        int cb2 = ci & 127, st = clsStart[cb2], n = clsCnt[cb2];
        for (int q = 0; q < n; ++q) {
            int j = items[st + q];
            if (j <= i || scls[j] != ci) continue;
            float4 bj = sbox[j];
            float xx1 = fmaxf(bi.x, bj.x);
            float yy1 = fmaxf(bi.y, bj.y);
            float xx2 = fminf(bi.z, bj.z);
            float yy2 = fminf(bi.w, bj.w);
            float ww = fmaxf(xx2 - xx1, 0.f);
            float hh2 = fmaxf(yy2 - yy1, 0.f);
            float inter = ww * hh2;
            float iou = inter / (ai + sarea[j] - inter);   // exact reference op order
            if (iou > 0.5f) {
                int p = atomicAdd(&npair, 1);
                if (p < PCAP) pairs[p] = ((u32)i << 10) | (u32)j;
            }
        }
    }
    __syncthreads();

    int P = npair; if (P > PCAP) P = PCAP;
    if (tid < P) {                      // rank-sort ascending; keys unique
        u32 k = pairs[tid];
        int rr = 0;
        for (int q = 0; q < P; ++q) rr += (pairs[q] < k);
        sorted[rr] = k;
    }
    __syncthreads();

    // greedy walk over sorted pairs; wave 0, lane l<16 owns sup word l
    if (wid == 0) {
        u64 sup = 0;
        for (int p = 0; p < P; ++p) {
            u32 k = sorted[p];
            int i = k >> 10;
            u64 supw = __shfl(sup, i >> 6);
            if (((supw >> (i & 63)) & 1ull) == 0ull) {   // i kept -> suppress j
                int j = (int)(k & 1023u);
                if (lane == (j >> 6)) sup |= 1ull << (j & 63);
            }
        }
        if (lane < 16) keepw[lane] = ~sup;
    }
    __syncthreads();

    float s0 = sscore[0];   // index 0 never suppressed; scores descending

    for (int i = tid; i < KTOP; i += 1024) {
        bool kp = (keepw[i >> 6] >> (i & 63)) & 1ull;
        if (kp && sscore[i] >= REL1 * s0) atomicMin(&firstIdx[scls[i] & 127], i);
    }
    __syncthreads();

    bool fin = false;
    if (tid < KTOP) {
        bool kp = (keepw[tid >> 6] >> (tid & 63)) & 1ull;
        bool v3 = kp && (sscore[tid] >= REL1 * s0);
        if (v3) {
            int f = firstIdx[scls[tid] & 127];
            bool del = (f < tid) && (sscore[tid] < REL2 * sscore[f]);
            fin = !del;
        }
    }
    u64 m = __ballot(fin);
    if (lane == 0) wtot[wid] = __popcll(m);
    __syncthreads();
    int prefix = 0, V = 0;
    for (int k = 0; k < 16; ++k) { int c = wtot[k]; if (k < wid) prefix += c; V += c; }
    int rank = prefix + __popcll(m & ((1ull << lane) - 1ull));

    float* ob = out;                          // boxes  [B,100,4]
    float* oc = out + (size_t)B * 400;        // classes[B,100] (as float)
    float* os = out + (size_t)B * 500;        // scores [B,100]
    if (fin && rank < 100) {
        int o = b * 100 + rank;
        float4 bx = sbox[tid];
        ob[o * 4 + 0] = bx.x;
        ob[o * 4 + 1] = bx.y;
        ob[o * 4 + 2] = bx.z;
        ob[o * 4 + 3] = bx.w;
        oc[o] = (float)scls[tid];
        os[o] = sscore[tid];
    }
    int Vc = V < 100 ? V : 100;
    if (tid >= Vc && tid < 100) {
        int o = b * 100 + tid;
        ob[o * 4 + 0] = 0.f;
        ob[o * 4 + 1] = 0.f;
        ob[o * 4 + 2] = 0.f;
        ob[o * 4 + 3] = 0.f;
        oc[o] = -1.f;
        os[o] = 0.f;
    }
}

extern "C" void kernel_launch(void* const* d_in, const int* in_sizes, int n_in,
                              void* d_out, int out_size, void* d_ws, size_t ws_size,
                              hipStream_t stream) {
    (void)n_in; (void)ws_size;
    float* out = (float*)d_out;
    int B = out_size / 600;          // 100*(4+1+1) per image

    // identify boxes input purely from sizes (4N vs N); robust to any permutation
    int ib = 0;
    for (int i = 1; i < 3; ++i) if (in_sizes[i] > in_sizes[ib]) ib = i;
    int o1 = -1, o2 = -1;
    for (int i = 0; i < 3; ++i) if (i != ib) { if (o1 < 0) o1 = i; else o2 = i; }
    int N = in_sizes[o1] / B;
    const float4* boxes = (const float4*)d_in[ib];
    const void* pA = d_in[o1];
    const void* pB = d_in[o2];

    char* ws = (char*)d_ws;
    size_t off = 0;
    auto alloc = [&](size_t bytes) { size_t r = off; off += (bytes + 255) & ~(size_t)255; return r; };
    size_t ph_off   = alloc((size_t)B * RBLK * NB * 4);   // 1 MB
    size_t cut_off  = alloc((size_t)B * 4);
    size_t cnt_off  = alloc((size_t)B * 4);
    size_t cand_off = alloc((size_t)B * CAP * 8);         // 512 KB

    int* phist = (int*)(ws + ph_off);
    int* cutf  = (int*)(ws + cut_off);
    int* cnt   = (int*)(ws + cnt_off);
    u64* cand64 = (u64*)(ws + cand_off);

    void* args[] = {(void*)&pA, (void*)&pB, (void*)&boxes, (void*)&N,
                    (void*)&phist, (void*)&cutf, (void*)&cnt, (void*)&cand64,
                    (void*)&out, (void*)&B};
    hipLaunchCooperativeKernel((const void*)fused_kernel, dim3(B * RBLK), dim3(1024),
                               args, 0, stream);
}

// Round 12
// 74.035 us; speedup vs baseline: 4.6881x; 4.6881x over previous
//
#include <hip/hip_runtime.h>

#define KTOP 1000
#define NB 1024
#define CAP 2048
#define PCAP 1024
#define HB 16              // hist/collect blocks per image
#define REL1 0.1f
#define REL2 0.05f

typedef unsigned long long u64;
typedef unsigned int u32;

__device__ __forceinline__ const float* pick_scores(const void* A, const void* B, int flag) {
    return flag ? (const float*)B : (const float*)A;   // flag=1 -> A is classes
}
__device__ __forceinline__ const int* pick_classes(const void* A, const void* B, int flag) {
    return flag ? (const int*)A : (const int*)B;
}

// flag=1 iff A looks like int class labels (all bit patterns < 256 over 256 probes).
__device__ __forceinline__ int block_flag256(const void* pA, int tid, int* ldsf) {
    if (tid == 0) *ldsf = 0;
    __syncthreads();
    if (tid < 256) {
        u32 v = ((const u32*)pA)[tid];
        u64 big = __ballot(v >= 256u);
        if ((tid & 63) == 0 && big) atomicOr(ldsf, 1);
    }
    __syncthreads();
    return *ldsf ? 0 : 1;
}

__device__ __forceinline__ int bucket_of(float v) {
    int bu = (int)(v * (float)NB);           // *1024 exact (pow2) -> monotone
    return bu < 0 ? 0 : (bu > NB - 1 ? NB - 1 : bu);
}

// ---- kernel 1: per-block partial histograms (plain stores); zero cnt[b] ----
__global__ __launch_bounds__(256) void hist_kernel(const void* __restrict__ pA,
                                                   const void* __restrict__ pB, int N,
                                                   int* __restrict__ phist,    // [B][HB][NB]
                                                   int* __restrict__ cnt) {
    __shared__ int h[NB];
    __shared__ int ldsf;
    int b = blockIdx.y, blk = blockIdx.x;
    int t = threadIdx.x;
    int flag = block_flag256(pA, t, &ldsf);
    for (int i = t; i < NB; i += 256) h[i] = 0;
    if (blk == 0 && t == 0) cnt[b] = 0;      // consumed by kernel 2 (stream-ordered)
    __syncthreads();
    const float* s = pick_scores(pA, pB, flag) + (size_t)b * N;
    const float4* s4 = (const float4*)s;
    int N4 = N >> 2;
    for (int i = blk * 256 + t; i < N4; i += HB * 256) {
        float4 v = s4[i];
        atomicAdd(&h[bucket_of(v.x)], 1);
        atomicAdd(&h[bucket_of(v.y)], 1);
        atomicAdd(&h[bucket_of(v.z)], 1);
        atomicAdd(&h[bucket_of(v.w)], 1);
    }
    for (int i = N4 * 4 + blk * 256 + t; i < N; i += HB * 256)
        atomicAdd(&h[bucket_of(s[i])], 1);
    __syncthreads();
    int4* dst = (int4*)(phist + ((size_t)b * HB + blk) * NB);
    dst[t] = make_int4(h[t * 4], h[t * 4 + 1], h[t * 4 + 2], h[t * 4 + 3]);
}

// ---- kernel 2: per-block cutoff recompute + count + prefix + one atomic + write keys ----
__global__ __launch_bounds__(256) void collect_kernel(const void* __restrict__ pA,
                                                      const void* __restrict__ pB, int N,
                                                      const int* __restrict__ phist,
                                                      int* __restrict__ cnt,
                                                      u64* __restrict__ cand64) {
    __shared__ int hh[NB];
    __shared__ int csum[256];
    __shared__ int pref[256];
    __shared__ int ldsf, scut, sbase;
    int b = blockIdx.y;
    int t = threadIdx.x;
    int flag = block_flag256(pA, t, &ldsf);

    // sum the HB partial histograms (L2-hot, 64KB/image)
    {
        const int4* src = (const int4*)(phist + (size_t)b * HB * NB);
        int4 acc = make_int4(0, 0, 0, 0);
#pragma unroll
        for (int k = 0; k < HB; ++k) {
            int4 v = src[k * (NB / 4) + t];
            acc.x += v.x; acc.y += v.y; acc.z += v.z; acc.w += v.w;
        }
        hh[t * 4] = acc.x; hh[t * 4 + 1] = acc.y; hh[t * 4 + 2] = acc.z; hh[t * 4 + 3] = acc.w;
    }
    __syncthreads();
    {
        int base = NB - 1 - t * (NB / 256);
        int a2 = 0;
#pragma unroll
        for (int k = 0; k < NB / 256; ++k) a2 += hh[base - k];
        csum[t] = a2;
    }
    __syncthreads();
    if (t == 0) {              // bucket of the KTOP-th largest score (verbatim logic)
        int cum = 0, cut = 0;
        for (int u = 0; u < 256; ++u) {
            if (cum + csum[u] >= KTOP) {
                for (int k = 0; k < NB / 256; ++k) {
                    cum += hh[NB - 1 - u * (NB / 256) - k];
                    if (cum >= KTOP) { cut = NB - 1 - u * (NB / 256) - k; break; }
                }
                break;
            }
            cum += csum[u];
        }
        scut = cut;
    }
    __syncthreads();
    int cut = scut;

    const float* s = pick_scores(pA, pB, flag) + (size_t)b * N;
    const float4* s4 = (const float4*)s;
    int N4 = N >> 2;
    int stride = HB * 256;

    int nloc = 0;
    for (int i = blockIdx.x * 256 + t; i < N4; i += stride) {
        float4 v = s4[i];
        nloc += (bucket_of(v.x) >= cut) + (bucket_of(v.y) >= cut) +
                (bucket_of(v.z) >= cut) + (bucket_of(v.w) >= cut);
    }
    for (int i = N4 * 4 + blockIdx.x * 256 + t; i < N; i += stride)
        nloc += (bucket_of(s[i]) >= cut);

    pref[t] = nloc;
    __syncthreads();
    if (t == 0) {
        int acc = 0;
        for (int k = 0; k < 256; ++k) { int c = pref[k]; pref[k] = acc; acc += c; }
        sbase = acc ? atomicAdd(&cnt[b], acc) : 0;
    }
    __syncthreads();
    if (nloc == 0) return;

    int pos = sbase + pref[t];
    u64* cb = cand64 + (size_t)b * CAP;
    for (int i = blockIdx.x * 256 + t; i < N4; i += stride) {    // L1-hot re-read
        float4 v = s4[i];
        float vv[4] = {v.x, v.y, v.z, v.w};
#pragma unroll
        for (int k = 0; k < 4; ++k) {
            if (bucket_of(vv[k]) >= cut) {
                if (pos < CAP)
                    cb[pos] = ((u64)__float_as_uint(vv[k]) << 32) | (u32)(~(u32)(i * 4 + k));
                ++pos;
            }
        }
    }
    for (int i = N4 * 4 + blockIdx.x * 256 + t; i < N; i += stride) {
        float v = s[i];
        if (bucket_of(v) >= cut) {
            if (pos < CAP)
                cb[pos] = ((u64)__float_as_uint(v) << 32) | (u32)(~(u32)i);
            ++pos;
        }
    }
}

// ---- kernel 3: rank + gather + class-bucketed NMS + thresholds + f32 output ----
__global__ __launch_bounds__(1024) void megafinish_kernel(const void* __restrict__ pA,
                                                          const void* __restrict__ pB,
                                                          const float4* __restrict__ boxes, int N,
                                                          const int* __restrict__ cnt,
                                                          const u64* __restrict__ cand64,
                                                          float* __restrict__ out, int B) {
    __shared__ u64 uni[CAP];          // key[] -> myPos/pairs/sorted (disjoint lifetimes)
    __shared__ float4 sbox[KTOP];
    __shared__ float sarea[KTOP];
    __shared__ float sscore[KTOP];
    __shared__ int scls[KTOP];
    __shared__ short items[KTOP];
    __shared__ int clsCnt[128];
    __shared__ int clsStart[128];
    __shared__ u64 keepw[16];
    __shared__ int firstIdx[128];
    __shared__ int wtot[16];
    __shared__ int ldsf, npair;

    u64* key    = uni;
    int* myPos  = (int*)uni;
    u32* pairs  = (u32*)uni;
    u32* sorted = ((u32*)uni) + PCAP;

    int b = blockIdx.x;
    int tid = threadIdx.x;
    int lane = tid & 63;
    int wid = tid >> 6;

    int flag = block_flag256(pA, tid, &ldsf);
    if (tid < 128) { clsCnt[tid] = 0; firstIdx[tid] = 0x7fffffff; }
    if (tid == 0) npair = 0;
    __syncthreads();

    int M = cnt[b]; if (M > CAP) M = CAP;
    for (int e = tid; e < M; e += 1024) key[e] = cand64[(size_t)b * CAP + e];
    __syncthreads();

    // rank-by-count: exact top_k order (score desc, ties -> lower idx); keys unique
    {
        int c0 = tid, c1 = tid + 1024;
        u64 kc0 = (c0 < M) ? key[c0] : 0;
        u64 kc1 = (c1 < M) ? key[c1] : 0;
        int r0 = 0, r1 = 0;
        for (int j = 0; j < M; ++j) {
            u64 kj = key[j];               // LDS broadcast
            r0 += (kj > kc0);
            r1 += (kj > kc1);
        }
        const int* classes = pick_classes(pA, pB, flag);
        if (c0 < M && r0 < KTOP) {
            int idx = (int)(~(u32)kc0);
            sscore[r0] = __uint_as_float((u32)(kc0 >> 32));
            scls[r0] = classes[(size_t)b * N + idx];
            sbox[r0] = boxes[(size_t)b * N + idx];
        }
        if (c1 < M && r1 < KTOP) {
            int idx = (int)(~(u32)kc1);
            sscore[r1] = __uint_as_float((u32)(kc1 >> 32));
            scls[r1] = classes[(size_t)b * N + idx];
            sbox[r1] = boxes[(size_t)b * N + idx];
        }
    }
    __syncthreads();   // key[] dead; uni reused

    // class bucketing
    if (tid < KTOP) {
        float4 bx = sbox[tid];
        sarea[tid] = (bx.z - bx.x) * (bx.w - bx.y);
        myPos[tid] = atomicAdd(&clsCnt[scls[tid] & 127], 1);
    }
    __syncthreads();
    if (tid == 0) {
        int acc = 0;
        for (int c = 0; c < 128; ++c) { clsStart[c] = acc; acc += clsCnt[c]; }
    }
    __syncthreads();
    if (tid < KTOP) items[clsStart[scls[tid] & 127] + myPos[tid]] = (short)tid;
    __syncthreads();   // myPos dead

    // pair finding within class buckets (avg ~12.5 entries)
    if (tid < KTOP) {
        int i = tid;
        float4 bi = sbox[i];
        float ai = sarea[i];
        int ci = scls[i];
        int cb2 = ci & 127, st = clsStart[cb2], n = clsCnt[cb2];
        for (int q = 0; q < n; ++q) {
            int j = items[st + q];
            if (j <= i || scls[j] != ci) continue;
            float4 bj = sbox[j];
            float xx1 = fmaxf(bi.x, bj.x);
            float yy1 = fmaxf(bi.y, bj.y);
            float xx2 = fminf(bi.z, bj.z);
            float yy2 = fminf(bi.w, bj.w);
            float ww = fmaxf(xx2 - xx1, 0.f);
            float hh2 = fmaxf(yy2 - yy1, 0.f);
            float inter = ww * hh2;
            float iou = inter / (ai + sarea[j] - inter);   // exact reference op order
            if (iou > 0.5f) {
                int p = atomicAdd(&npair, 1);
                if (p < PCAP) pairs[p] = ((u32)i << 10) | (u32)j;
            }
        }
    }
    __syncthreads();

    int P = npair; if (P > PCAP) P = PCAP;
    if (tid < P) {                      // rank-sort ascending; keys unique
        u32 k = pairs[tid];
        int rr = 0;
        for (int q = 0; q < P; ++q) rr += (pairs[q] < k);
        sorted[rr] = k;
    }
    __syncthreads();

    // greedy walk over sorted pairs; wave 0, lane l<16 owns sup word l
    if (wid == 0) {
        u64 sup = 0;
        for (int p = 0; p < P; ++p) {
            u32 k = sorted[p];
            int i = k >> 10;
            u64 supw = __shfl(sup, i >> 6);
            if (((supw >> (i & 63)) & 1ull) == 0ull) {   // i kept -> suppress j
                int j = (int)(k & 1023u);
                if (lane == (j >> 6)) sup |= 1ull << (j & 63);
            }
        }
        if (lane < 16) keepw[lane] = ~sup;
    }
    __syncthreads();

    float s0 = sscore[0];   // index 0 never suppressed; scores descending

    for (int i = tid; i < KTOP; i += 1024) {
        bool kp = (keepw[i >> 6] >> (i & 63)) & 1ull;
        if (kp && sscore[i] >= REL1 * s0) atomicMin(&firstIdx[scls[i] & 127], i);
    }
    __syncthreads();

    bool fin = false;
    if (tid < KTOP) {
        bool kp = (keepw[tid >> 6] >> (tid & 63)) & 1ull;
        bool v3 = kp && (sscore[tid] >= REL1 * s0);
        if (v3) {
            int f = firstIdx[scls[tid] & 127];
            bool del = (f < tid) && (sscore[tid] < REL2 * sscore[f]);
            fin = !del;
        }
    }
    u64 m = __ballot(fin);
    if (lane == 0) wtot[wid] = __popcll(m);
    __syncthreads();
    int prefix = 0, V = 0;
    for (int k = 0; k < 16; ++k) { int c = wtot[k]; if (k < wid) prefix += c; V += c; }
    int rank = prefix + __popcll(m & ((1ull << lane) - 1ull));

    float* ob = out;                          // boxes  [B,100,4]
    float* oc = out + (size_t)B * 400;        // classes[B,100] (as float)
    float* os = out + (size_t)B * 500;        // scores [B,100]
    if (fin && rank < 100) {
        int o = b * 100 + rank;
        float4 bx = sbox[tid];
        ob[o * 4 + 0] = bx.x;
        ob[o * 4 + 1] = bx.y;
        ob[o * 4 + 2] = bx.z;
        ob[o * 4 + 3] = bx.w;
        oc[o] = (float)scls[tid];
        os[o] = sscore[tid];
    }
    int Vc = V < 100 ? V : 100;
    if (tid >= Vc && tid < 100) {
        int o = b * 100 + tid;
        ob[o * 4 + 0] = 0.f;
        ob[o * 4 + 1] = 0.f;
        ob[o * 4 + 2] = 0.f;
        ob[o * 4 + 3] = 0.f;
        oc[o] = -1.f;
        os[o] = 0.f;
    }
}

extern "C" void kernel_launch(void* const* d_in, const int* in_sizes, int n_in,
                              void* d_out, int out_size, void* d_ws, size_t ws_size,
                              hipStream_t stream) {
    (void)n_in; (void)ws_size;
    float* out = (float*)d_out;
    int B = out_size / 600;          // 100*(4+1+1) per image

    // identify boxes input purely from sizes (4N vs N); robust to any permutation
    int ib = 0;
    for (int i = 1; i < 3; ++i) if (in_sizes[i] > in_sizes[ib]) ib = i;
    int o1 = -1, o2 = -1;
    for (int i = 0; i < 3; ++i) if (i != ib) { if (o1 < 0) o1 = i; else o2 = i; }
    int N = in_sizes[o1] / B;
    const float4* boxes = (const float4*)d_in[ib];
    const void* pA = d_in[o1];
    const void* pB = d_in[o2];

    char* ws = (char*)d_ws;
    size_t off = 0;
    auto alloc = [&](size_t bytes) { size_t r = off; off += (bytes + 255) & ~(size_t)255; return r; };
    size_t ph_off   = alloc((size_t)B * HB * NB * 4);     // 2 MB
    size_t cnt_off  = alloc((size_t)B * 4);
    size_t cand_off = alloc((size_t)B * CAP * 8);         // 512 KB

    int* phist  = (int*)(ws + ph_off);
    int* cnt    = (int*)(ws + cnt_off);
    u64* cand64 = (u64*)(ws + cand_off);

    hist_kernel<<<dim3(HB, B), 256, 0, stream>>>(pA, pB, N, phist, cnt);
    collect_kernel<<<dim3(HB, B), 256, 0, stream>>>(pA, pB, N, phist, cnt, cand64);
    megafinish_kernel<<<B, 1024, 0, stream>>>(pA, pB, boxes, N, cnt, cand64, out, B);
}

// Round 13
// 68.832 us; speedup vs baseline: 5.0425x; 1.0756x over previous
//
#include <hip/hip_runtime.h>

#define KTOP 1000
#define NB 1024
#define CAP 2048
#define PCAP 1024
#define HB 16              // hist/collect blocks per image
#define REL1 0.1f
#define REL2 0.05f

typedef unsigned long long u64;
typedef unsigned int u32;

__device__ __forceinline__ const float* pick_scores(const void* A, const void* B, int flag) {
    return flag ? (const float*)B : (const float*)A;   // flag=1 -> A is classes
}
__device__ __forceinline__ const int* pick_classes(const void* A, const void* B, int flag) {
    return flag ? (const int*)A : (const int*)B;
}

// flag=1 iff A looks like int class labels (all bit patterns < 256 over 256 probes).
__device__ __forceinline__ int block_flag256(const void* pA, int tid, int* ldsf) {
    if (tid == 0) *ldsf = 0;
    __syncthreads();
    if (tid < 256) {
        u32 v = ((const u32*)pA)[tid];
        u64 big = __ballot(v >= 256u);
        if ((tid & 63) == 0 && big) atomicOr(ldsf, 1);
    }
    __syncthreads();
    return *ldsf ? 0 : 1;
}

// 64-thread variant: each lane probes 4 values
__device__ __forceinline__ int wave_flag256(const void* pA, int tid, int* ldsf) {
    if (tid == 0) *ldsf = 0;
    __syncthreads();
    if (tid < 64) {
        const u32* a = (const u32*)pA;
        u32 mx = 0;
#pragma unroll
        for (int k = 0; k < 4; ++k) { u32 v = a[tid * 4 + k]; mx = mx > v ? mx : v; }
        u64 big = __ballot(mx >= 256u);
        if (tid == 0 && big) *ldsf = 1;
    }
    __syncthreads();
    return *ldsf ? 0 : 1;
}

__device__ __forceinline__ int bucket_of(float v) {
    int bu = (int)(v * (float)NB);           // *1024 exact (pow2) -> monotone
    return bu < 0 ? 0 : (bu > NB - 1 ? NB - 1 : bu);
}

// ---- kernel 1: per-block partial histograms (plain stores); zero cnt[b] ----
__global__ __launch_bounds__(256) void hist_kernel(const void* __restrict__ pA,
                                                   const void* __restrict__ pB, int N,
                                                   int* __restrict__ phist,    // [B][HB][NB]
                                                   int* __restrict__ cnt) {
    __shared__ int h[NB];
    __shared__ int ldsf;
    int b = blockIdx.y, blk = blockIdx.x;
    int t = threadIdx.x;
    int flag = block_flag256(pA, t, &ldsf);
    for (int i = t; i < NB; i += 256) h[i] = 0;
    if (blk == 0 && t == 0) cnt[b] = 0;      // consumed by kernel 2 (stream-ordered)
    __syncthreads();
    const float* s = pick_scores(pA, pB, flag) + (size_t)b * N;
    const float4* s4 = (const float4*)s;
    int N4 = N >> 2;
    for (int i = blk * 256 + t; i < N4; i += HB * 256) {
        float4 v = s4[i];
        atomicAdd(&h[bucket_of(v.x)], 1);
        atomicAdd(&h[bucket_of(v.y)], 1);
        atomicAdd(&h[bucket_of(v.z)], 1);
        atomicAdd(&h[bucket_of(v.w)], 1);
    }
    for (int i = N4 * 4 + blk * 256 + t; i < N; i += HB * 256)
        atomicAdd(&h[bucket_of(s[i])], 1);
    __syncthreads();
    int4* dst = (int4*)(phist + ((size_t)b * HB + blk) * NB);
    dst[t] = make_int4(h[t * 4], h[t * 4 + 1], h[t * 4 + 2], h[t * 4 + 3]);
}

// ---- kernel 2: per-block cutoff recompute + count + prefix + one atomic + write keys ----
__global__ __launch_bounds__(256) void collect_kernel(const void* __restrict__ pA,
                                                      const void* __restrict__ pB, int N,
                                                      const int* __restrict__ phist,
                                                      int* __restrict__ cnt,
                                                      u64* __restrict__ cand64) {
    __shared__ int hh[NB];
    __shared__ int csum[256];
    __shared__ int pref[256];
    __shared__ int ldsf, scut, sbase;
    int b = blockIdx.y;
    int t = threadIdx.x;
    int flag = block_flag256(pA, t, &ldsf);

    // sum the HB partial histograms (L2-hot, 64KB/image)
    {
        const int4* src = (const int4*)(phist + (size_t)b * HB * NB);
        int4 acc = make_int4(0, 0, 0, 0);
#pragma unroll
        for (int k = 0; k < HB; ++k) {
            int4 v = src[k * (NB / 4) + t];
            acc.x += v.x; acc.y += v.y; acc.z += v.z; acc.w += v.w;
        }
        hh[t * 4] = acc.x; hh[t * 4 + 1] = acc.y; hh[t * 4 + 2] = acc.z; hh[t * 4 + 3] = acc.w;
    }
    __syncthreads();
    {
        int base = NB - 1 - t * (NB / 256);
        int a2 = 0;
#pragma unroll
        for (int k = 0; k < NB / 256; ++k) a2 += hh[base - k];
        csum[t] = a2;
    }
    __syncthreads();
    if (t == 0) {              // bucket of the KTOP-th largest score (verbatim logic)
        int cum = 0, cut = 0;
        for (int u = 0; u < 256; ++u) {
            if (cum + csum[u] >= KTOP) {
                for (int k = 0; k < NB / 256; ++k) {
                    cum += hh[NB - 1 - u * (NB / 256) - k];
                    if (cum >= KTOP) { cut = NB - 1 - u * (NB / 256) - k; break; }
                }
                break;
            }
            cum += csum[u];
        }
        scut = cut;
    }
    __syncthreads();
    int cut = scut;

    const float* s = pick_scores(pA, pB, flag) + (size_t)b * N;
    const float4* s4 = (const float4*)s;
    int N4 = N >> 2;
    int stride = HB * 256;

    int nloc = 0;
    for (int i = blockIdx.x * 256 + t; i < N4; i += stride) {
        float4 v = s4[i];
        nloc += (bucket_of(v.x) >= cut) + (bucket_of(v.y) >= cut) +
                (bucket_of(v.z) >= cut) + (bucket_of(v.w) >= cut);
    }
    for (int i = N4 * 4 + blockIdx.x * 256 + t; i < N; i += stride)
        nloc += (bucket_of(s[i]) >= cut);

    pref[t] = nloc;
    __syncthreads();
    if (t == 0) {
        int acc = 0;
        for (int k = 0; k < 256; ++k) { int c = pref[k]; pref[k] = acc; acc += c; }
        sbase = acc ? atomicAdd(&cnt[b], acc) : 0;
    }
    __syncthreads();
    if (nloc == 0) return;

    int pos = sbase + pref[t];
    u64* cb = cand64 + (size_t)b * CAP;
    for (int i = blockIdx.x * 256 + t; i < N4; i += stride) {    // L1-hot re-read
        float4 v = s4[i];
        float vv[4] = {v.x, v.y, v.z, v.w};
#pragma unroll
        for (int k = 0; k < 4; ++k) {
            if (bucket_of(vv[k]) >= cut) {
                if (pos < CAP)
                    cb[pos] = ((u64)__float_as_uint(vv[k]) << 32) | (u32)(~(u32)(i * 4 + k));
                ++pos;
            }
        }
    }
    for (int i = N4 * 4 + blockIdx.x * 256 + t; i < N; i += stride) {
        float v = s[i];
        if (bucket_of(v) >= cut) {
            if (pos < CAP)
                cb[pos] = ((u64)__float_as_uint(v) << 32) | (u32)(~(u32)i);
            ++pos;
        }
    }
}

// ---- kernel 3: rank-by-count, shaped as 1 wave/CU, 4 cands/thread, b128 LDS reads ----
__global__ __launch_bounds__(64) void rank_kernel(const void* __restrict__ pA,
                                                  const void* __restrict__ pB,
                                                  const float4* __restrict__ boxes, int N,
                                                  const int* __restrict__ cnt,
                                                  const u64* __restrict__ cand64,
                                                  float* __restrict__ scores_k,
                                                  int* __restrict__ classes_k,
                                                  float4* __restrict__ boxes_k) {
    __shared__ __align__(16) u64 key[CAP + 2];
    __shared__ int ldsf;
    int b = blockIdx.y, blk = blockIdx.x, tid = threadIdx.x;
    int flag = wave_flag256(pA, tid, &ldsf);
    const int* classes = pick_classes(pA, pB, flag);

    int M = cnt[b]; if (M > CAP) M = CAP;
    for (int e = tid; e < M; e += 64) key[e] = cand64[(size_t)b * CAP + e];
    if (tid == 0 && (M & 1)) key[M] = 0;       // pad for paired reads (0 never counts)
    __syncthreads();

    // 4 candidates per thread, static indices
    int c0 = blk * 256 + tid;
    int c1 = c0 + 64, c2 = c0 + 128, c3 = c0 + 192;
    u64 k0 = (c0 < M) ? key[c0] : ~0ull;       // ~0 sentinel: rank stays >= M? no: nothing > ~0
    u64 k1 = (c1 < M) ? key[c1] : ~0ull;
    u64 k2 = (c2 < M) ? key[c2] : ~0ull;
    u64 k3 = (c3 < M) ? key[c3] : ~0ull;
    int r0 = 0, r1 = 0, r2 = 0, r3 = 0;
    int Me = M + (M & 1);
    for (int j = 0; j < Me; j += 2) {
        ulonglong2 kv = *reinterpret_cast<const ulonglong2*>(&key[j]);  // ds_read_b128 broadcast
        r0 += (kv.x > k0) + (kv.y > k0);
        r1 += (kv.x > k1) + (kv.y > k1);
        r2 += (kv.x > k2) + (kv.y > k2);
        r3 += (kv.x > k3) + (kv.y > k3);
    }
    u64 kk[4] = {k0, k1, k2, k3};
    int cc[4] = {c0, c1, c2, c3};
    int rr[4] = {r0, r1, r2, r3};
#pragma unroll
    for (int q = 0; q < 4; ++q) {
        if (cc[q] < M && rr[q] < KTOP) {
            int idx = (int)(~(u32)kk[q]);
            int r = rr[q];
            scores_k[(size_t)b * KTOP + r] = __uint_as_float((u32)(kk[q] >> 32));
            classes_k[(size_t)b * KTOP + r] = classes[(size_t)b * N + idx];
            boxes_k[(size_t)b * KTOP + r] = boxes[(size_t)b * N + idx];
        }
    }
}

// ---- kernel 4: class-bucketed pair finding + greedy scan + thresholds + f32 output ----
__global__ __launch_bounds__(1024) void finish_kernel(const float* __restrict__ scores_k,
                                                      const int* __restrict__ classes_k,
                                                      const float4* __restrict__ boxes_k,
                                                      float* __restrict__ out, int B) {
    __shared__ float4 sbox[KTOP];
    __shared__ float sarea[KTOP];
    __shared__ float sscore[KTOP];
    __shared__ int scls[KTOP];
    __shared__ int myPos[KTOP];
    __shared__ short items[KTOP];
    __shared__ int clsCnt[128];
    __shared__ int clsStart[128];
    __shared__ u32 pairs[PCAP];
    __shared__ u32 sorted[PCAP];
    __shared__ u64 keepw[16];
    __shared__ int firstIdx[128];
    __shared__ int wtot[16];
    __shared__ int npair;

    int b = blockIdx.x;
    int tid = threadIdx.x;
    int lane = tid & 63;
    int wid = tid >> 6;

    if (tid < 128) { clsCnt[tid] = 0; firstIdx[tid] = 0x7fffffff; }
    if (tid == 0) npair = 0;
    __syncthreads();

    if (tid < KTOP) {
        float4 bx = boxes_k[(size_t)b * KTOP + tid];
        sbox[tid] = bx;
        sarea[tid] = (bx.z - bx.x) * (bx.w - bx.y);
        sscore[tid] = scores_k[(size_t)b * KTOP + tid];
        int c = classes_k[(size_t)b * KTOP + tid];
        scls[tid] = c;
        myPos[tid] = atomicAdd(&clsCnt[c & 127], 1);
    }
    __syncthreads();
    if (tid == 0) {
        int acc = 0;
        for (int c = 0; c < 128; ++c) { clsStart[c] = acc; acc += clsCnt[c]; }
    }
    __syncthreads();
    if (tid < KTOP) items[clsStart[scls[tid] & 127] + myPos[tid]] = (short)tid;
    __syncthreads();

    // pair finding within class buckets (avg ~12.5 entries)
    if (tid < KTOP) {
        int i = tid;
        float4 bi = sbox[i];
        float ai = sarea[i];
        int ci = scls[i];
        int cb2 = ci & 127, st = clsStart[cb2], n = clsCnt[cb2];
        for (int q = 0; q < n; ++q) {
            int j = items[st + q];
            if (j <= i || scls[j] != ci) continue;
            float4 bj = sbox[j];
            float xx1 = fmaxf(bi.x, bj.x);
            float yy1 = fmaxf(bi.y, bj.y);
            float xx2 = fminf(bi.z, bj.z);
            float yy2 = fminf(bi.w, bj.w);
            float ww = fmaxf(xx2 - xx1, 0.f);
            float hh2 = fmaxf(yy2 - yy1, 0.f);
            float inter = ww * hh2;
            float iou = inter / (ai + sarea[j] - inter);   // exact reference op order
            if (iou > 0.5f) {
                int p = atomicAdd(&npair, 1);
                if (p < PCAP) pairs[p] = ((u32)i << 10) | (u32)j;
            }
        }
    }
    __syncthreads();

    int P = npair; if (P > PCAP) P = PCAP;
    if (tid < P) {                      // rank-sort ascending; keys unique
        u32 k = pairs[tid];
        int rr = 0;
        for (int q = 0; q < P; ++q) rr += (pairs[q] < k);
        sorted[rr] = k;
    }
    __syncthreads();

    // greedy walk over sorted pairs; wave 0, lane l<16 owns sup word l
    if (wid == 0) {
        u64 sup = 0;
        for (int p = 0; p < P; ++p) {
            u32 k = sorted[p];
            int i = k >> 10;
            u64 supw = __shfl(sup, i >> 6);
            if (((supw >> (i & 63)) & 1ull) == 0ull) {   // i kept -> suppress j
                int j = (int)(k & 1023u);
                if (lane == (j >> 6)) sup |= 1ull << (j & 63);
            }
        }
        if (lane < 16) keepw[lane] = ~sup;
    }
    __syncthreads();

    float s0 = sscore[0];   // index 0 never suppressed; scores descending

    for (int i = tid; i < KTOP; i += 1024) {
        bool kp = (keepw[i >> 6] >> (i & 63)) & 1ull;
        if (kp && sscore[i] >= REL1 * s0) atomicMin(&firstIdx[scls[i] & 127], i);
    }
    __syncthreads();

    bool fin = false;
    if (tid < KTOP) {
        bool kp = (keepw[tid >> 6] >> (tid & 63)) & 1ull;
        bool v3 = kp && (sscore[tid] >= REL1 * s0);
        if (v3) {
            int f = firstIdx[scls[tid] & 127];
            bool del = (f < tid) && (sscore[tid] < REL2 * sscore[f]);
            fin = !del;
        }
    }
    u64 m = __ballot(fin);
    if (lane == 0) wtot[wid] = __popcll(m);
    __syncthreads();
    int prefix = 0, V = 0;
    for (int k = 0; k < 16; ++k) { int c = wtot[k]; if (k < wid) prefix += c; V += c; }
    int rank = prefix + __popcll(m & ((1ull << lane) - 1ull));

    float* ob = out;                          // boxes  [B,100,4]
    float* oc = out + (size_t)B * 400;        // classes[B,100] (as float)
    float* os = out + (size_t)B * 500;        // scores [B,100]
    if (fin && rank < 100) {
        int o = b * 100 + rank;
        float4 bx = sbox[tid];
        ob[o * 4 + 0] = bx.x;
        ob[o * 4 + 1] = bx.y;
        ob[o * 4 + 2] = bx.z;
        ob[o * 4 + 3] = bx.w;
        oc[o] = (float)scls[tid];
        os[o] = sscore[tid];
    }
    int Vc = V < 100 ? V : 100;
    if (tid >= Vc && tid < 100) {
        int o = b * 100 + tid;
        ob[o * 4 + 0] = 0.f;
        ob[o * 4 + 1] = 0.f;
        ob[o * 4 + 2] = 0.f;
        ob[o * 4 + 3] = 0.f;
        oc[o] = -1.f;
        os[o] = 0.f;
    }
}

extern "C" void kernel_launch(void* const* d_in, const int* in_sizes, int n_in,
                              void* d_out, int out_size, void* d_ws, size_t ws_size,
                              hipStream_t stream) {
    (void)n_in; (void)ws_size;
    float* out = (float*)d_out;
    int B = out_size / 600;          // 100*(4+1+1) per image

    // identify boxes input purely from sizes (4N vs N); robust to any permutation
    int ib = 0;
    for (int i = 1; i < 3; ++i) if (in_sizes[i] > in_sizes[ib]) ib = i;
    int o1 = -1, o2 = -1;
    for (int i = 0; i < 3; ++i) if (i != ib) { if (o1 < 0) o1 = i; else o2 = i; }
    int N = in_sizes[o1] / B;
    const float4* boxes = (const float4*)d_in[ib];
    const void* pA = d_in[o1];
    const void* pB = d_in[o2];

    char* ws = (char*)d_ws;
    size_t off = 0;
    auto alloc = [&](size_t bytes) { size_t r = off; off += (bytes + 255) & ~(size_t)255; return r; };
    size_t ph_off   = alloc((size_t)B * HB * NB * 4);     // 2 MB
    size_t cnt_off  = alloc((size_t)B * 4);
    size_t cand_off = alloc((size_t)B * CAP * 8);         // 512 KB
    size_t sk_off   = alloc((size_t)B * KTOP * 4);
    size_t ck_off   = alloc((size_t)B * KTOP * 4);
    size_t bk_off   = alloc((size_t)B * KTOP * 16);

    int* phist  = (int*)(ws + ph_off);
    int* cnt    = (int*)(ws + cnt_off);
    u64* cand64 = (u64*)(ws + cand_off);
    float* scores_k = (float*)(ws + sk_off);
    int* classes_k  = (int*)(ws + ck_off);
    float4* boxes_k = (float4*)(ws + bk_off);

    hist_kernel<<<dim3(HB, B), 256, 0, stream>>>(pA, pB, N, phist, cnt);
    collect_kernel<<<dim3(HB, B), 256, 0, stream>>>(pA, pB, N, phist, cnt, cand64);
    rank_kernel<<<dim3(8, B), 64, 0, stream>>>(pA, pB, boxes, N, cnt, cand64,
                                               scores_k, classes_k, boxes_k);
    finish_kernel<<<B, 1024, 0, stream>>>(scores_k, classes_k, boxes_k, out, B);
}

// Round 14
// 55.382 us; speedup vs baseline: 6.2671x; 1.2429x over previous
//
#include <hip/hip_runtime.h>

#define KTOP 1000
#define NB 1024
#define CAP 2048
#define PCAP 1024
#define HB 16              // hist/collect blocks per image
#define REL1 0.1f
#define REL2 0.05f

typedef unsigned long long u64;
typedef unsigned int u32;

__device__ __forceinline__ const float* pick_scores(const void* A, const void* B, int flag) {
    return flag ? (const float*)B : (const float*)A;   // flag=1 -> A is classes
}
__device__ __forceinline__ const int* pick_classes(const void* A, const void* B, int flag) {
    return flag ? (const int*)A : (const int*)B;
}

// flag=1 iff A looks like int class labels (all bit patterns < 256 over 256 probes).
__device__ __forceinline__ int block_flag256(const void* pA, int tid, int* ldsf) {
    if (tid == 0) *ldsf = 0;
    __syncthreads();
    if (tid < 256) {
        u32 v = ((const u32*)pA)[tid];
        u64 big = __ballot(v >= 256u);
        if ((tid & 63) == 0 && big) atomicOr(ldsf, 1);
    }
    __syncthreads();
    return *ldsf ? 0 : 1;
}

__device__ __forceinline__ int bucket_of(float v) {
    int bu = (int)(v * (float)NB);           // *1024 exact (pow2) -> monotone
    return bu < 0 ? 0 : (bu > NB - 1 ? NB - 1 : bu);
}

// ---- kernel 1: per-block partial histograms (plain stores); zero gbcnt ----
__global__ __launch_bounds__(256) void hist_kernel(const void* __restrict__ pA,
                                                   const void* __restrict__ pB, int N,
                                                   int* __restrict__ phist,    // [B][HB][NB]
                                                   int* __restrict__ gbcnt) {  // [B][NB]
    __shared__ int h[NB];
    __shared__ int ldsf;
    int b = blockIdx.y, blk = blockIdx.x;
    int t = threadIdx.x;
    int flag = block_flag256(pA, t, &ldsf);
    for (int i = t; i < NB; i += 256) h[i] = 0;
    if (t < 64) gbcnt[(size_t)b * NB + blk * 64 + t] = 0;   // 16 blocks x 64 = NB
    __syncthreads();
    const float* s = pick_scores(pA, pB, flag) + (size_t)b * N;
    const float4* s4 = (const float4*)s;
    int N4 = N >> 2;
    for (int i = blk * 256 + t; i < N4; i += HB * 256) {
        float4 v = s4[i];
        atomicAdd(&h[bucket_of(v.x)], 1);
        atomicAdd(&h[bucket_of(v.y)], 1);
        atomicAdd(&h[bucket_of(v.z)], 1);
        atomicAdd(&h[bucket_of(v.w)], 1);
    }
    for (int i = N4 * 4 + blk * 256 + t; i < N; i += HB * 256)
        atomicAdd(&h[bucket_of(s[i])], 1);
    __syncthreads();
    int4* dst = (int4*)(phist + ((size_t)b * HB + blk) * NB);
    dst[t] = make_int4(h[t * 4], h[t * 4 + 1], h[t * 4 + 2], h[t * 4 + 3]);
}

// ---- kernel 2: cutoff + bucket starts + single-pass bucket-grouped candidate write ----
__global__ __launch_bounds__(256) void collect_kernel(const void* __restrict__ pA,
                                                      const void* __restrict__ pB, int N,
                                                      const int* __restrict__ phist,
                                                      int* __restrict__ gbcnt,
                                                      int* __restrict__ gbs,   // [B][NB]
                                                      int* __restrict__ gbe,   // [B][NB]
                                                      int* __restrict__ cnt,   // [B] total M
                                                      u64* __restrict__ cand64) {
    __shared__ int hh[NB];
    __shared__ int csum[256];
    __shared__ int bstart[NB];
    __shared__ int ldsf, scut;
    int b = blockIdx.y;
    int t = threadIdx.x;
    int flag = block_flag256(pA, t, &ldsf);

    // sum the HB partial histograms (L2-hot)
    {
        const int4* src = (const int4*)(phist + (size_t)b * HB * NB);
        int4 acc = make_int4(0, 0, 0, 0);
#pragma unroll
        for (int k = 0; k < HB; ++k) {
            int4 v = src[k * (NB / 4) + t];
            acc.x += v.x; acc.y += v.y; acc.z += v.z; acc.w += v.w;
        }
        hh[t * 4] = acc.x; hh[t * 4 + 1] = acc.y; hh[t * 4 + 2] = acc.z; hh[t * 4 + 3] = acc.w;
    }
    __syncthreads();
    {   // group sums: group t = buckets [NB-1-4t-3 .. NB-1-4t], descending
        int base = NB - 1 - t * 4;
        csum[t] = hh[base] + hh[base - 1] + hh[base - 2] + hh[base - 3];
    }
    __syncthreads();
    if (t == 0) {
        // cutoff: bucket of the KTOP-th largest score (verbatim proven logic)
        int cum = 0, cut = 0;
        for (int u = 0; u < 256; ++u) {
            if (cum + csum[u] >= KTOP) {
                for (int k = 0; k < 4; ++k) {
                    cum += hh[NB - 1 - u * 4 - k];
                    if (cum >= KTOP) { cut = NB - 1 - u * 4 - k; break; }
                }
                break;
            }
            cum += csum[u];
        }
        scut = cut;
        // in-place exclusive prefix over groups (descending order)
        int run = 0;
        for (int g = 0; g < 256; ++g) { int c = csum[g]; csum[g] = run; run += c; }
    }
    __syncthreads();
    {   // bucket starts: keys in strictly-higher buckets
        int gp = csum[t];
        int base = NB - 1 - t * 4;
        int h0 = hh[base], h1 = hh[base - 1], h2 = hh[base - 2];
        bstart[base]     = gp;
        bstart[base - 1] = gp + h0;
        bstart[base - 2] = gp + h0 + h1;
        bstart[base - 3] = gp + h0 + h1 + h2;
    }
    __syncthreads();
    int cut = scut;

    if (blockIdx.x == 0) {      // export bucket ranges + total
        int base = NB - 1 - t * 4;
#pragma unroll
        for (int k = 0; k < 4; ++k) {
            int bu = base - k;
            gbs[(size_t)b * NB + bu] = bstart[bu];
            gbe[(size_t)b * NB + bu] = bstart[bu] + hh[bu];
        }
        if (t == 0) cnt[b] = bstart[cut] + hh[cut];
    }

    // single pass: slot = bstart[bu] + per-bucket global atomic (bucket-grouped layout)
    const float* s = pick_scores(pA, pB, flag) + (size_t)b * N;
    const float4* s4 = (const float4*)s;
    int N4 = N >> 2;
    int stride = HB * 256;
    int* bc = gbcnt + (size_t)b * NB;
    u64* cb = cand64 + (size_t)b * CAP;
    for (int i = blockIdx.x * 256 + t; i < N4; i += stride) {
        float4 v = s4[i];
        float vv[4] = {v.x, v.y, v.z, v.w};
#pragma unroll
        for (int k = 0; k < 4; ++k) {
            int bu = bucket_of(vv[k]);
            if (bu >= cut) {
                int pos = bstart[bu] + atomicAdd(&bc[bu], 1);
                if (pos < CAP)
                    cb[pos] = ((u64)__float_as_uint(vv[k]) << 32) | (u32)(~(u32)(i * 4 + k));
            }
        }
    }
    for (int i = N4 * 4 + blockIdx.x * 256 + t; i < N; i += stride) {
        float v = s[i];
        int bu = bucket_of(v);
        if (bu >= cut) {
            int pos = bstart[bu] + atomicAdd(&bc[bu], 1);
            if (pos < CAP)
                cb[pos] = ((u64)__float_as_uint(v) << 32) | (u32)(~(u32)i);
        }
    }
}

// ---- kernel 3: bucket-local rank (global rank = bstart + within-bucket count) + gather ----
__global__ __launch_bounds__(256) void rank_kernel(const void* __restrict__ pA,
                                                   const void* __restrict__ pB,
                                                   const float4* __restrict__ boxes, int N,
                                                   const int* __restrict__ cnt,
                                                   const u64* __restrict__ cand64,
                                                   const int* __restrict__ gbs,
                                                   const int* __restrict__ gbe,
                                                   float* __restrict__ scores_k,
                                                   int* __restrict__ classes_k,
                                                   float4* __restrict__ boxes_k) {
    __shared__ int ldsf;
    int b = blockIdx.y, tid = threadIdx.x;
    int flag = block_flag256(pA, tid, &ldsf);
    const int* classes = pick_classes(pA, pB, flag);

    int M = cnt[b]; if (M > CAP) M = CAP;
    int c = blockIdx.x * 256 + tid;
    if (c >= M) return;
    const u64* cb = cand64 + (size_t)b * CAP;
    u64 k = cb[c];
    float sc = __uint_as_float((u32)(k >> 32));
    int bu = bucket_of(sc);            // same float -> same bucket as collect
    int st = gbs[(size_t)b * NB + bu];
    int en = gbe[(size_t)b * NB + bu]; if (en > CAP) en = CAP;
    int r = st;                        // all keys in higher buckets are greater (monotone)
    for (int j = st; j < en; ++j) r += (cb[j] > k);   // L1-hot, ~41 iters avg
    if (r < KTOP) {
        int idx = (int)(~(u32)k);
        scores_k[(size_t)b * KTOP + r] = sc;
        classes_k[(size_t)b * KTOP + r] = classes[(size_t)b * N + idx];
        boxes_k[(size_t)b * KTOP + r] = boxes[(size_t)b * N + idx];
    }
}

// ---- kernel 4: class-bucketed pair finding + greedy scan + thresholds + f32 output ----
__global__ __launch_bounds__(1024) void finish_kernel(const float* __restrict__ scores_k,
                                                      const int* __restrict__ classes_k,
                                                      const float4* __restrict__ boxes_k,
                                                      float* __restrict__ out, int B) {
    __shared__ float4 sbox[KTOP];
    __shared__ float sarea[KTOP];
    __shared__ float sscore[KTOP];
    __shared__ int scls[KTOP];
    __shared__ int myPos[KTOP];
    __shared__ short items[KTOP];
    __shared__ int clsCnt[128];
    __shared__ int clsStart[128];
    __shared__ u32 pairs[PCAP];
    __shared__ u32 sorted[PCAP];
    __shared__ u64 keepw[16];
    __shared__ int firstIdx[128];
    __shared__ int wtot[16];
    __shared__ int npair;

    int b = blockIdx.x;
    int tid = threadIdx.x;
    int lane = tid & 63;
    int wid = tid >> 6;

    if (tid < 128) { clsCnt[tid] = 0; firstIdx[tid] = 0x7fffffff; }
    if (tid == 0) npair = 0;
    __syncthreads();

    if (tid < KTOP) {
        float4 bx = boxes_k[(size_t)b * KTOP + tid];
        sbox[tid] = bx;
        sarea[tid] = (bx.z - bx.x) * (bx.w - bx.y);
        sscore[tid] = scores_k[(size_t)b * KTOP + tid];
        int c = classes_k[(size_t)b * KTOP + tid];
        scls[tid] = c;
        myPos[tid] = atomicAdd(&clsCnt[c & 127], 1);
    }
    __syncthreads();
    if (tid == 0) {
        int acc = 0;
        for (int c = 0; c < 128; ++c) { clsStart[c] = acc; acc += clsCnt[c]; }
    }
    __syncthreads();
    if (tid < KTOP) items[clsStart[scls[tid] & 127] + myPos[tid]] = (short)tid;
    __syncthreads();

    // pair finding within class buckets (avg ~12.5 entries)
    if (tid < KTOP) {
        int i = tid;
        float4 bi = sbox[i];
        float ai = sarea[i];
        int ci = scls[i];
        int cb2 = ci & 127, st = clsStart[cb2], n = clsCnt[cb2];
        for (int q = 0; q < n; ++q) {
            int j = items[st + q];
            if (j <= i || scls[j] != ci) continue;
            float4 bj = sbox[j];
            float xx1 = fmaxf(bi.x, bj.x);
            float yy1 = fmaxf(bi.y, bj.y);
            float xx2 = fminf(bi.z, bj.z);
            float yy2 = fminf(bi.w, bj.w);
            float ww = fmaxf(xx2 - xx1, 0.f);
            float hh2 = fmaxf(yy2 - yy1, 0.f);
            float inter = ww * hh2;
            float iou = inter / (ai + sarea[j] - inter);   // exact reference op order
            if (iou > 0.5f) {
                int p = atomicAdd(&npair, 1);
                if (p < PCAP) pairs[p] = ((u32)i << 10) | (u32)j;
            }
        }
    }
    __syncthreads();

    int P = npair; if (P > PCAP) P = PCAP;
    if (tid < P) {                      // rank-sort ascending; keys unique
        u32 k = pairs[tid];
        int rr = 0;
        for (int q = 0; q < P; ++q) rr += (pairs[q] < k);
        sorted[rr] = k;
    }
    __syncthreads();

    // greedy walk over sorted pairs; wave 0, lane l<16 owns sup word l
    if (wid == 0) {
        u64 sup = 0;
        for (int p = 0; p < P; ++p) {
            u32 k = sorted[p];
            int i = k >> 10;
            u64 supw = __shfl(sup, i >> 6);
            if (((supw >> (i & 63)) & 1ull) == 0ull) {   // i kept -> suppress j
                int j = (int)(k & 1023u);
                if (lane == (j >> 6)) sup |= 1ull << (j & 63);
            }
        }
        if (lane < 16) keepw[lane] = ~sup;
    }
    __syncthreads();

    float s0 = sscore[0];   // index 0 never suppressed; scores descending

    for (int i = tid; i < KTOP; i += 1024) {
        bool kp = (keepw[i >> 6] >> (i & 63)) & 1ull;
        if (kp && sscore[i] >= REL1 * s0) atomicMin(&firstIdx[scls[i] & 127], i);
    }
    __syncthreads();

    bool fin = false;
    if (tid < KTOP) {
        bool kp = (keepw[tid >> 6] >> (tid & 63)) & 1ull;
        bool v3 = kp && (sscore[tid] >= REL1 * s0);
        if (v3) {
            int f = firstIdx[scls[tid] & 127];
            bool del = (f < tid) && (sscore[tid] < REL2 * sscore[f]);
            fin = !del;
        }
    }
    u64 m = __ballot(fin);
    if (lane == 0) wtot[wid] = __popcll(m);
    __syncthreads();
    int prefix = 0, V = 0;
    for (int k = 0; k < 16; ++k) { int c = wtot[k]; if (k < wid) prefix += c; V += c; }
    int rank = prefix + __popcll(m & ((1ull << lane) - 1ull));

    float* ob = out;                          // boxes  [B,100,4]
    float* oc = out + (size_t)B * 400;        // classes[B,100] (as float)
    float* os = out + (size_t)B * 500;        // scores [B,100]
    if (fin && rank < 100) {
        int o = b * 100 + rank;
        float4 bx = sbox[tid];
        ob[o * 4 + 0] = bx.x;
        ob[o * 4 + 1] = bx.y;
        ob[o * 4 + 2] = bx.z;
        ob[o * 4 + 3] = bx.w;
        oc[o] = (float)scls[tid];
        os[o] = sscore[tid];
    }
    int Vc = V < 100 ? V : 100;
    if (tid >= Vc && tid < 100) {
        int o = b * 100 + tid;
        ob[o * 4 + 0] = 0.f;
        ob[o * 4 + 1] = 0.f;
        ob[o * 4 + 2] = 0.f;
        ob[o * 4 + 3] = 0.f;
        oc[o] = -1.f;
        os[o] = 0.f;
    }
}

extern "C" void kernel_launch(void* const* d_in, const int* in_sizes, int n_in,
                              void* d_out, int out_size, void* d_ws, size_t ws_size,
                              hipStream_t stream) {
    (void)n_in; (void)ws_size;
    float* out = (float*)d_out;
    int B = out_size / 600;          // 100*(4+1+1) per image

    // identify boxes input purely from sizes (4N vs N); robust to any permutation
    int ib = 0;
    for (int i = 1; i < 3; ++i) if (in_sizes[i] > in_sizes[ib]) ib = i;
    int o1 = -1, o2 = -1;
    for (int i = 0; i < 3; ++i) if (i != ib) { if (o1 < 0) o1 = i; else o2 = i; }
    int N = in_sizes[o1] / B;
    const float4* boxes = (const float4*)d_in[ib];
    const void* pA = d_in[o1];
    const void* pB = d_in[o2];

    char* ws = (char*)d_ws;
    size_t off = 0;
    auto alloc = [&](size_t bytes) { size_t r = off; off += (bytes + 255) & ~(size_t)255; return r; };
    size_t ph_off   = alloc((size_t)B * HB * NB * 4);     // 2 MB
    size_t bc_off   = alloc((size_t)B * NB * 4);          // gbcnt
    size_t bs_off   = alloc((size_t)B * NB * 4);          // gbs
    size_t be_off   = alloc((size_t)B * NB * 4);          // gbe
    size_t cnt_off  = alloc((size_t)B * 4);
    size_t cand_off = alloc((size_t)B * CAP * 8);         // 512 KB
    size_t sk_off   = alloc((size_t)B * KTOP * 4);
    size_t ck_off   = alloc((size_t)B * KTOP * 4);
    size_t bk_off   = alloc((size_t)B * KTOP * 16);

    int* phist  = (int*)(ws + ph_off);
    int* gbcnt  = (int*)(ws + bc_off);
    int* gbs    = (int*)(ws + bs_off);
    int* gbe    = (int*)(ws + be_off);
    int* cnt    = (int*)(ws + cnt_off);
    u64* cand64 = (u64*)(ws + cand_off);
    float* scores_k = (float*)(ws + sk_off);
    int* classes_k  = (int*)(ws + ck_off);
    float4* boxes_k = (float4*)(ws + bk_off);

    hist_kernel<<<dim3(HB, B), 256, 0, stream>>>(pA, pB, N, phist, gbcnt);
    collect_kernel<<<dim3(HB, B), 256, 0, stream>>>(pA, pB, N, phist, gbcnt,
                                                    gbs, gbe, cnt, cand64);
    rank_kernel<<<dim3(8, B), 256, 0, stream>>>(pA, pB, boxes, N, cnt, cand64,
                                                gbs, gbe, scores_k, classes_k, boxes_k);
    finish_kernel<<<B, 1024, 0, stream>>>(scores_k, classes_k, boxes_k, out, B);
}

// Round 15
// 54.615 us; speedup vs baseline: 6.3551x; 1.0141x over previous
//
#include <hip/hip_runtime.h>

#define KTOP 1000
#define NB 1024
#define CAP 2048
#define PCAP 1024
#define HB 16              // hist/collect blocks per image (1024 threads each)
#define REL1 0.1f
#define REL2 0.05f

typedef unsigned long long u64;
typedef unsigned int u32;

__device__ __forceinline__ const float* pick_scores(const void* A, const void* B, int flag) {
    return flag ? (const float*)B : (const float*)A;   // flag=1 -> A is classes
}
__device__ __forceinline__ const int* pick_classes(const void* A, const void* B, int flag) {
    return flag ? (const int*)A : (const int*)B;
}

// flag=1 iff A looks like int class labels (all bit patterns < 256 over 256 probes).
__device__ __forceinline__ int block_flag256(const void* pA, int tid, int* ldsf) {
    if (tid == 0) *ldsf = 0;
    __syncthreads();
    if (tid < 256) {
        u32 v = ((const u32*)pA)[tid];
        u64 big = __ballot(v >= 256u);
        if ((tid & 63) == 0 && big) atomicOr(ldsf, 1);
    }
    __syncthreads();
    return *ldsf ? 0 : 1;
}

__device__ __forceinline__ int bucket_of(float v) {
    int bu = (int)(v * (float)NB);           // *1024 exact (pow2) -> monotone
    return bu < 0 ? 0 : (bu > NB - 1 ? NB - 1 : bu);
}

// ---- kernel 1: per-block partial histograms (plain stores) ----
__global__ __launch_bounds__(1024) void hist_kernel(const void* __restrict__ pA,
                                                    const void* __restrict__ pB, int N,
                                                    int* __restrict__ phist) {  // [B][HB][NB]
    __shared__ int h[NB];
    __shared__ int ldsf;
    int b = blockIdx.y, blk = blockIdx.x;
    int t = threadIdx.x;
    int flag = block_flag256(pA, t, &ldsf);
    h[t] = 0;                                // NB == blockDim
    __syncthreads();
    const float* s = pick_scores(pA, pB, flag) + (size_t)b * N;
    const float4* s4 = (const float4*)s;
    int N4 = N >> 2;
    for (int i = blk * 1024 + t; i < N4; i += HB * 1024) {
        float4 v = s4[i];
        atomicAdd(&h[bucket_of(v.x)], 1);
        atomicAdd(&h[bucket_of(v.y)], 1);
        atomicAdd(&h[bucket_of(v.z)], 1);
        atomicAdd(&h[bucket_of(v.w)], 1);
    }
    for (int i = N4 * 4 + blk * 1024 + t; i < N; i += HB * 1024)
        atomicAdd(&h[bucket_of(s[i])], 1);
    __syncthreads();
    phist[((size_t)b * HB + blk) * NB + t] = h[t];
}

// ---- kernel 2: exact-base bucket-grouped collect (NO global atomics) ----
// blockBase[bu] = bstart[bu] + sum_{k<blk} phist[b][k][bu]; within-block order
// via LDS counters. Deterministic layout; slot arithmetic exact by construction.
__global__ __launch_bounds__(1024) void collect_kernel(const void* __restrict__ pA,
                                                       const void* __restrict__ pB, int N,
                                                       const int* __restrict__ phist,
                                                       int* __restrict__ gbs,   // [B][NB]
                                                       int* __restrict__ gbe,   // [B][NB]
                                                       int* __restrict__ cnt,   // [B] total M
                                                       u64* __restrict__ cand64) {
    __shared__ int hh[NB];       // full per-image histogram
    __shared__ int bb[NB];       // this block's base per bucket (excl prefix, then += bstart)
    __shared__ int bcL[NB];      // within-block LDS counters
    __shared__ int csum[256];
    __shared__ int ldsf, scut;
    int b = blockIdx.y, blk = blockIdx.x;
    int t = threadIdx.x;
    int flag = block_flag256(pA, t, &ldsf);

    {   // sum partials; simultaneously accumulate this block's exclusive prefix
        const int* src = phist + (size_t)b * HB * NB;
        int acc = 0, excl = 0;
#pragma unroll
        for (int k = 0; k < HB; ++k) {
            int v = src[k * NB + t];         // coalesced
            acc += v;
            if (k < blk) excl += v;
        }
        hh[t] = acc;
        bb[t] = excl;
        bcL[t] = 0;
    }
    __syncthreads();
    if (t < 256) {   // group sums, descending groups of 4
        int base = NB - 1 - t * 4;
        csum[t] = hh[base] + hh[base - 1] + hh[base - 2] + hh[base - 3];
    }
    __syncthreads();
    if (t == 0) {
        // cutoff: bucket of the KTOP-th largest score (verbatim proven logic)
        int cum = 0, cut = 0;
        for (int u = 0; u < 256; ++u) {
            if (cum + csum[u] >= KTOP) {
                for (int k = 0; k < 4; ++k) {
                    cum += hh[NB - 1 - u * 4 - k];
                    if (cum >= KTOP) { cut = NB - 1 - u * 4 - k; break; }
                }
                break;
            }
            cum += csum[u];
        }
        scut = cut;
        int run = 0;   // in-place exclusive prefix over groups (descending)
        for (int g = 0; g < 256; ++g) { int c = csum[g]; csum[g] = run; run += c; }
    }
    __syncthreads();
    if (t < 256) {   // bb[bu] += bstart[bu] (keys in strictly-higher buckets)
        int gp = csum[t];
        int base = NB - 1 - t * 4;
        int h0 = hh[base], h1 = hh[base - 1], h2 = hh[base - 2];
        bb[base]     += gp;
        bb[base - 1] += gp + h0;
        bb[base - 2] += gp + h0 + h1;
        bb[base - 3] += gp + h0 + h1 + h2;
    }
    __syncthreads();
    int cut = scut;

    if (blk == 0) {     // block 0: excl==0, so bb == bstart -> export ranges + total
        gbs[(size_t)b * NB + t] = bb[t];
        gbe[(size_t)b * NB + t] = bb[t] + hh[t];
        if (t == 0) cnt[b] = bb[cut] + hh[cut];
    }

    const float* s = pick_scores(pA, pB, flag) + (size_t)b * N;
    const float4* s4 = (const float4*)s;
    int N4 = N >> 2;
    u64* cb = cand64 + (size_t)b * CAP;
    for (int i = blk * 1024 + t; i < N4; i += HB * 1024) {
        float4 v = s4[i];
        float vv[4] = {v.x, v.y, v.z, v.w};
#pragma unroll
        for (int k = 0; k < 4; ++k) {
            int bu = bucket_of(vv[k]);
            if (bu >= cut) {
                int pos = bb[bu] + atomicAdd(&bcL[bu], 1);   // LDS atomic only
                if (pos < CAP)
                    cb[pos] = ((u64)__float_as_uint(vv[k]) << 32) | (u32)(~(u32)(i * 4 + k));
            }
        }
    }
    for (int i = N4 * 4 + blk * 1024 + t; i < N; i += HB * 1024) {
        float v = s[i];
        int bu = bucket_of(v);
        if (bu >= cut) {
            int pos = bb[bu] + atomicAdd(&bcL[bu], 1);
            if (pos < CAP)
                cb[pos] = ((u64)__float_as_uint(v) << 32) | (u32)(~(u32)i);
        }
    }
}

// ---- kernel 3: bucket-local rank -> LDS gather -> class-bucketed NMS -> output ----
__global__ __launch_bounds__(1024) void rankfinish_kernel(const void* __restrict__ pA,
                                                          const void* __restrict__ pB,
                                                          const float4* __restrict__ boxes, int N,
                                                          const int* __restrict__ cnt,
                                                          const u64* __restrict__ cand64,
                                                          const int* __restrict__ gbs,
                                                          const int* __restrict__ gbe,
                                                          float* __restrict__ out, int B) {
    __shared__ float4 sbox[KTOP];
    __shared__ float sarea[KTOP];
    __shared__ float sscore[KTOP];
    __shared__ int scls[KTOP];
    __shared__ int myPos[KTOP];
    __shared__ short items[KTOP];
    __shared__ int clsCnt[128];
    __shared__ int clsStart[128];
    __shared__ u32 pairs[PCAP];
    __shared__ u32 sorted[PCAP];
    __shared__ u64 keepw[16];
    __shared__ int firstIdx[128];
    __shared__ int wtot[16];
    __shared__ int ldsf, npair;

    int b = blockIdx.x;
    int tid = threadIdx.x;
    int lane = tid & 63;
    int wid = tid >> 6;

    int flag = block_flag256(pA, tid, &ldsf);
    const int* classes = pick_classes(pA, pB, flag);
    if (tid < 128) { clsCnt[tid] = 0; firstIdx[tid] = 0x7fffffff; }
    if (tid == 0) npair = 0;
    __syncthreads();

    // phase 0: bucket-local rank (global rank = bstart + within-bucket count) + gather
    int M = cnt[b]; if (M > CAP) M = CAP;
    const u64* cb = cand64 + (size_t)b * CAP;
    for (int c = tid; c < M; c += 1024) {
        u64 k = cb[c];
        float sc = __uint_as_float((u32)(k >> 32));
        int bu = bucket_of(sc);
        int st = gbs[(size_t)b * NB + bu];
        int en = gbe[(size_t)b * NB + bu]; if (en > CAP) en = CAP;
        int r = st;
        for (int j = st; j < en; ++j) r += (cb[j] > k);   // L2-hot, ~41 iters avg
        if (r < KTOP) {
            int idx = (int)(~(u32)k);
            sscore[r] = sc;
            scls[r] = classes[(size_t)b * N + idx];
            sbox[r] = boxes[(size_t)b * N + idx];
        }
    }
    __syncthreads();

    // class bucketing
    if (tid < KTOP) {
        float4 bx = sbox[tid];
        sarea[tid] = (bx.z - bx.x) * (bx.w - bx.y);
        myPos[tid] = atomicAdd(&clsCnt[scls[tid] & 127], 1);
    }
    __syncthreads();
    if (tid == 0) {
        int acc = 0;
        for (int c = 0; c < 128; ++c) { clsStart[c] = acc; acc += clsCnt[c]; }
    }
    __syncthreads();
    if (tid < KTOP) items[clsStart[scls[tid] & 127] + myPos[tid]] = (short)tid;
    __syncthreads();

    // pair finding within class buckets (avg ~12.5 entries)
    if (tid < KTOP) {
        int i = tid;
        float4 bi = sbox[i];
        float ai = sarea[i];
        int ci = scls[i];
        int cb2 = ci & 127, st = clsStart[cb2], n = clsCnt[cb2];
        for (int q = 0; q < n; ++q) {
            int j = items[st + q];
            if (j <= i || scls[j] != ci) continue;
            float4 bj = sbox[j];
            float xx1 = fmaxf(bi.x, bj.x);
            float yy1 = fmaxf(bi.y, bj.y);
            float xx2 = fminf(bi.z, bj.z);
            float yy2 = fminf(bi.w, bj.w);
            float ww = fmaxf(xx2 - xx1, 0.f);
            float hh2 = fmaxf(yy2 - yy1, 0.f);
            float inter = ww * hh2;
            float iou = inter / (ai + sarea[j] - inter);   // exact reference op order
            if (iou > 0.5f) {
                int p = atomicAdd(&npair, 1);
                if (p < PCAP) pairs[p] = ((u32)i << 10) | (u32)j;
            }
        }
    }
    __syncthreads();

    int P = npair; if (P > PCAP) P = PCAP;
    if (tid < P) {                      // rank-sort ascending; keys unique
        u32 k = pairs[tid];
        int rr = 0;
        for (int q = 0; q < P; ++q) rr += (pairs[q] < k);
        sorted[rr] = k;
    }
    __syncthreads();

    // greedy walk over sorted pairs; wave 0, lane l<16 owns sup word l
    if (wid == 0) {
        u64 sup = 0;
        for (int p = 0; p < P; ++p) {
            u32 k = sorted[p];
            int i = k >> 10;
            u64 supw = __shfl(sup, i >> 6);
            if (((supw >> (i & 63)) & 1ull) == 0ull) {   // i kept -> suppress j
                int j = (int)(k & 1023u);
                if (lane == (j >> 6)) sup |= 1ull << (j & 63);
            }
        }
        if (lane < 16) keepw[lane] = ~sup;
    }
    __syncthreads();

    float s0 = sscore[0];   // index 0 never suppressed; scores descending

    for (int i = tid; i < KTOP; i += 1024) {
        bool kp = (keepw[i >> 6] >> (i & 63)) & 1ull;
        if (kp && sscore[i] >= REL1 * s0) atomicMin(&firstIdx[scls[i] & 127], i);
    }
    __syncthreads();

    bool fin = false;
    if (tid < KTOP) {
        bool kp = (keepw[tid >> 6] >> (tid & 63)) & 1ull;
        bool v3 = kp && (sscore[tid] >= REL1 * s0);
        if (v3) {
            int f = firstIdx[scls[tid] & 127];
            bool del = (f < tid) && (sscore[tid] < REL2 * sscore[f]);
            fin = !del;
        }
    }
    u64 m = __ballot(fin);
    if (lane == 0) wtot[wid] = __popcll(m);
    __syncthreads();
    int prefix = 0, V = 0;
    for (int k = 0; k < 16; ++k) { int c = wtot[k]; if (k < wid) prefix += c; V += c; }
    int rank = prefix + __popcll(m & ((1ull << lane) - 1ull));

    float* ob = out;                          // boxes  [B,100,4]
    float* oc = out + (size_t)B * 400;        // classes[B,100] (as float)
    float* os = out + (size_t)B * 500;        // scores [B,100]
    if (fin && rank < 100) {
        int o = b * 100 + rank;
        float4 bx = sbox[tid];
        ob[o * 4 + 0] = bx.x;
        ob[o * 4 + 1] = bx.y;
        ob[o * 4 + 2] = bx.z;
        ob[o * 4 + 3] = bx.w;
        oc[o] = (float)scls[tid];
        os[o] = sscore[tid];
    }
    int Vc = V < 100 ? V : 100;
    if (tid >= Vc && tid < 100) {
        int o = b * 100 + tid;
        ob[o * 4 + 0] = 0.f;
        ob[o * 4 + 1] = 0.f;
        ob[o * 4 + 2] = 0.f;
        ob[o * 4 + 3] = 0.f;
        oc[o] = -1.f;
        os[o] = 0.f;
    }
}

extern "C" void kernel_launch(void* const* d_in, const int* in_sizes, int n_in,
                              void* d_out, int out_size, void* d_ws, size_t ws_size,
                              hipStream_t stream) {
    (void)n_in; (void)ws_size;
    float* out = (float*)d_out;
    int B = out_size / 600;          // 100*(4+1+1) per image

    // identify boxes input purely from sizes (4N vs N); robust to any permutation
    int ib = 0;
    for (int i = 1; i < 3; ++i) if (in_sizes[i] > in_sizes[ib]) ib = i;
    int o1 = -1, o2 = -1;
    for (int i = 0; i < 3; ++i) if (i != ib) { if (o1 < 0) o1 = i; else o2 = i; }
    int N = in_sizes[o1] / B;
    const float4* boxes = (const float4*)d_in[ib];
    const void* pA = d_in[o1];
    const void* pB = d_in[o2];

    char* ws = (char*)d_ws;
    size_t off = 0;
    auto alloc = [&](size_t bytes) { size_t r = off; off += (bytes + 255) & ~(size_t)255; return r; };
    size_t ph_off   = alloc((size_t)B * HB * NB * 4);     // 2 MB
    size_t bs_off   = alloc((size_t)B * NB * 4);          // gbs
    size_t be_off   = alloc((size_t)B * NB * 4);          // gbe
    size_t cnt_off  = alloc((size_t)B * 4);
    size_t cand_off = alloc((size_t)B * CAP * 8);         // 512 KB

    int* phist  = (int*)(ws + ph_off);
    int* gbs    = (int*)(ws + bs_off);
    int* gbe    = (int*)(ws + be_off);
    int* cnt    = (int*)(ws + cnt_off);
    u64* cand64 = (u64*)(ws + cand_off);

    hist_kernel<<<dim3(HB, B), 1024, 0, stream>>>(pA, pB, N, phist);
    collect_kernel<<<dim3(HB, B), 1024, 0, stream>>>(pA, pB, N, phist,
                                                     gbs, gbe, cnt, cand64);
    rankfinish_kernel<<<B, 1024, 0, stream>>>(pA, pB, boxes, N, cnt, cand64,
                                              gbs, gbe, out, B);
}

// Round 16
// 43.960 us; speedup vs baseline: 7.8954x; 1.2424x over previous
//
#include <hip/hip_runtime.h>

#define KTOP 1000
#define NB 1024
#define CAP 2048
#define PCAP 1024
#define HB 16              // hist/collect blocks per image (1024 threads each)
#define REL1 0.1f
#define REL2 0.05f

typedef unsigned long long u64;
typedef unsigned int u32;

__device__ __forceinline__ const float* pick_scores(const void* A, const void* B, int flag) {
    return flag ? (const float*)B : (const float*)A;   // flag=1 -> A is classes
}
__device__ __forceinline__ const int* pick_classes(const void* A, const void* B, int flag) {
    return flag ? (const int*)A : (const int*)B;
}

// flag=1 iff A looks like int class labels (all bit patterns < 256 over 256 probes).
__device__ __forceinline__ int block_flag256(const void* pA, int tid, int* ldsf) {
    if (tid == 0) *ldsf = 0;
    __syncthreads();
    if (tid < 256) {
        u32 v = ((const u32*)pA)[tid];
        u64 big = __ballot(v >= 256u);
        if ((tid & 63) == 0 && big) atomicOr(ldsf, 1);
    }
    __syncthreads();
    return *ldsf ? 0 : 1;
}

__device__ __forceinline__ int bucket_of(float v) {
    int bu = (int)(v * (float)NB);           // *1024 exact (pow2) -> monotone
    return bu < 0 ? 0 : (bu > NB - 1 ? NB - 1 : bu);
}

// ---- kernel 1: per-block partial histograms (plain stores) ----
__global__ __launch_bounds__(1024) void hist_kernel(const void* __restrict__ pA,
                                                    const void* __restrict__ pB, int N,
                                                    int* __restrict__ phist) {  // [B][HB][NB]
    __shared__ int h[NB];
    __shared__ int ldsf;
    int b = blockIdx.y, blk = blockIdx.x;
    int t = threadIdx.x;
    int flag = block_flag256(pA, t, &ldsf);
    h[t] = 0;                                // NB == blockDim
    __syncthreads();
    const float* s = pick_scores(pA, pB, flag) + (size_t)b * N;
    const float4* s4 = (const float4*)s;
    int N4 = N >> 2;
    for (int i = blk * 1024 + t; i < N4; i += HB * 1024) {
        float4 v = s4[i];
        atomicAdd(&h[bucket_of(v.x)], 1);
        atomicAdd(&h[bucket_of(v.y)], 1);
        atomicAdd(&h[bucket_of(v.z)], 1);
        atomicAdd(&h[bucket_of(v.w)], 1);
    }
    for (int i = N4 * 4 + blk * 1024 + t; i < N; i += HB * 1024)
        atomicAdd(&h[bucket_of(s[i])], 1);
    __syncthreads();
    phist[((size_t)b * HB + blk) * NB + t] = h[t];
}

// ---- kernel 2: exact-base bucket-grouped collect; also gathers box+class ----
// blockBase[bu] = bstart[bu] + sum_{k<blk} phist[b][k][bu]; within-block order via
// LDS counters (no global atomics). Scattered boxes/classes loads happen HERE at
// full occupancy (32 waves/CU) where they hide under the score stream.
__global__ __launch_bounds__(1024) void collect_kernel(const void* __restrict__ pA,
                                                       const void* __restrict__ pB,
                                                       const float4* __restrict__ boxes, int N,
                                                       const int* __restrict__ phist,
                                                       int* __restrict__ gbs,   // [B][NB]
                                                       int* __restrict__ gbe,   // [B][NB]
                                                       int* __restrict__ cnt,   // [B] total M
                                                       u64* __restrict__ ckey,  // [B][CAP]
                                                       float4* __restrict__ cbox,// [B][CAP]
                                                       int* __restrict__ ccls) { // [B][CAP]
    __shared__ int hh[NB];       // full per-image histogram
    __shared__ int bb[NB];       // this block's base per bucket
    __shared__ int bcL[NB];      // within-block LDS counters
    __shared__ int csum[256];
    __shared__ int ldsf, scut;
    int b = blockIdx.y, blk = blockIdx.x;
    int t = threadIdx.x;
    int flag = block_flag256(pA, t, &ldsf);
    const int* classes = pick_classes(pA, pB, flag);

    {   // sum partials; simultaneously accumulate this block's exclusive prefix
        const int* src = phist + (size_t)b * HB * NB;
        int acc = 0, excl = 0;
#pragma unroll
        for (int k = 0; k < HB; ++k) {
            int v = src[k * NB + t];         // coalesced
            acc += v;
            if (k < blk) excl += v;
        }
        hh[t] = acc;
        bb[t] = excl;
        bcL[t] = 0;
    }
    __syncthreads();
    if (t < 256) {   // group sums, descending groups of 4
        int base = NB - 1 - t * 4;
        csum[t] = hh[base] + hh[base - 1] + hh[base - 2] + hh[base - 3];
    }
    __syncthreads();
    if (t == 0) {
        // cutoff: bucket of the KTOP-th largest score (verbatim proven logic)
        int cum = 0, cut = 0;
        for (int u = 0; u < 256; ++u) {
            if (cum + csum[u] >= KTOP) {
                for (int k = 0; k < 4; ++k) {
                    cum += hh[NB - 1 - u * 4 - k];
                    if (cum >= KTOP) { cut = NB - 1 - u * 4 - k; break; }
                }
                break;
            }
            cum += csum[u];
        }
        scut = cut;
        int run = 0;   // in-place exclusive prefix over groups (descending)
        for (int g = 0; g < 256; ++g) { int c = csum[g]; csum[g] = run; run += c; }
    }
    __syncthreads();
    if (t < 256) {   // bb[bu] += bstart[bu] (keys in strictly-higher buckets)
        int gp = csum[t];
        int base = NB - 1 - t * 4;
        int h0 = hh[base], h1 = hh[base - 1], h2 = hh[base - 2];
        bb[base]     += gp;
        bb[base - 1] += gp + h0;
        bb[base - 2] += gp + h0 + h1;
        bb[base - 3] += gp + h0 + h1 + h2;
    }
    __syncthreads();
    int cut = scut;

    if (blk == 0) {     // block 0: excl==0 so bb == bstart -> export ranges + total
        gbs[(size_t)b * NB + t] = bb[t];
        gbe[(size_t)b * NB + t] = bb[t] + hh[t];
        if (t == 0) cnt[b] = bb[cut] + hh[cut];
    }

    const float* s = pick_scores(pA, pB, flag) + (size_t)b * N;
    const float4* s4 = (const float4*)s;
    int N4 = N >> 2;
    u64* kb = ckey + (size_t)b * CAP;
    float4* xb = cbox + (size_t)b * CAP;
    int* lb = ccls + (size_t)b * CAP;
    for (int i = blk * 1024 + t; i < N4; i += HB * 1024) {
        float4 v = s4[i];
        float vv[4] = {v.x, v.y, v.z, v.w};
#pragma unroll
        for (int k = 0; k < 4; ++k) {
            int bu = bucket_of(vv[k]);
            if (bu >= cut) {
                int pos = bb[bu] + atomicAdd(&bcL[bu], 1);   // LDS atomic only
                if (pos < CAP) {
                    int idx = i * 4 + k;
                    kb[pos] = ((u64)__float_as_uint(vv[k]) << 32) | (u32)(~(u32)idx);
                    xb[pos] = boxes[(size_t)b * N + idx];
                    lb[pos] = classes[(size_t)b * N + idx];
                }
            }
        }
    }
    for (int i = N4 * 4 + blk * 1024 + t; i < N; i += HB * 1024) {
        float v = s[i];
        int bu = bucket_of(v);
        if (bu >= cut) {
            int pos = bb[bu] + atomicAdd(&bcL[bu], 1);
            if (pos < CAP) {
                kb[pos] = ((u64)__float_as_uint(v) << 32) | (u32)(~(u32)i);
                xb[pos] = boxes[(size_t)b * N + i];
                lb[pos] = classes[(size_t)b * N + i];
            }
        }
    }
}

// ---- kernel 3: LDS bucket-local rank -> NMS -> output (all reads contiguous) ----
__global__ __launch_bounds__(1024) void finish_kernel(const int* __restrict__ cnt,
                                                      const u64* __restrict__ ckey,
                                                      const float4* __restrict__ cbox,
                                                      const int* __restrict__ ccls,
                                                      const int* __restrict__ gbs,
                                                      const int* __restrict__ gbe,
                                                      float* __restrict__ out, int B) {
    __shared__ u64 uni[CAP];        // phase0: key[]; later myPos/pairs/sorted
    __shared__ int gbsL[NB];
    __shared__ int gbeL[NB];
    __shared__ float4 sbox[KTOP];
    __shared__ float sarea[KTOP];
    __shared__ float sscore[KTOP];
    __shared__ int scls[KTOP];
    __shared__ short items[KTOP];
    __shared__ int clsCnt[128];
    __shared__ int clsStart[128];
    __shared__ u64 keepw[16];
    __shared__ int firstIdx[128];
    __shared__ int wtot[16];
    __shared__ int npair;

    u64* key    = uni;
    int* myPos  = (int*)uni;
    u32* pairs  = (u32*)uni;
    u32* sorted = ((u32*)uni) + PCAP;

    int b = blockIdx.x;
    int tid = threadIdx.x;
    int lane = tid & 63;
    int wid = tid >> 6;

    if (tid < 128) { clsCnt[tid] = 0; firstIdx[tid] = 0x7fffffff; }
    if (tid == 0) npair = 0;
    gbsL[tid] = gbs[(size_t)b * NB + tid];      // contiguous
    gbeL[tid] = gbe[(size_t)b * NB + tid];
    int M = cnt[b]; if (M > CAP) M = CAP;
    const u64* kb = ckey + (size_t)b * CAP;
    for (int e = tid; e < M; e += 1024) key[e] = kb[e];   // contiguous
    __syncthreads();

    // phase 0: bucket-local rank in LDS (global rank = bstart + within-bucket count)
    for (int c = tid; c < M; c += 1024) {
        u64 k = key[c];
        float sc = __uint_as_float((u32)(k >> 32));
        int bu = bucket_of(sc);
        int st = gbsL[bu];
        int en = gbeL[bu]; if (en > CAP) en = CAP;
        int r = st;
        for (int j = st; j < en; ++j) r += (key[j] > k);   // LDS, ~98 iters avg
        if (r < KTOP) {
            sscore[r] = sc;
            scls[r] = ccls[(size_t)b * CAP + c];           // contiguous in c
            sbox[r] = cbox[(size_t)b * CAP + c];
        }
    }
    __syncthreads();   // key[] dead; uni reused

    // class bucketing
    if (tid < KTOP) {
        float4 bx = sbox[tid];
        sarea[tid] = (bx.z - bx.x) * (bx.w - bx.y);
        myPos[tid] = atomicAdd(&clsCnt[scls[tid] & 127], 1);
    }
    __syncthreads();
    if (tid == 0) {
        int acc = 0;
        for (int c = 0; c < 128; ++c) { clsStart[c] = acc; acc += clsCnt[c]; }
    }
    __syncthreads();
    if (tid < KTOP) items[clsStart[scls[tid] & 127] + myPos[tid]] = (short)tid;
    __syncthreads();   // myPos dead

    // pair finding within class buckets (avg ~12.5 entries)
    if (tid < KTOP) {
        int i = tid;
        float4 bi = sbox[i];
        float ai = sarea[i];
        int ci = scls[i];
        int cb2 = ci & 127, st = clsStart[cb2], n = clsCnt[cb2];
        for (int q = 0; q < n; ++q) {
            int j = items[st + q];
            if (j <= i || scls[j] != ci) continue;
            float4 bj = sbox[j];
            float xx1 = fmaxf(bi.x, bj.x);
            float yy1 = fmaxf(bi.y, bj.y);
            float xx2 = fminf(bi.z, bj.z);
            float yy2 = fminf(bi.w, bj.w);
            float ww = fmaxf(xx2 - xx1, 0.f);
            float hh2 = fmaxf(yy2 - yy1, 0.f);
            float inter = ww * hh2;
            float iou = inter / (ai + sarea[j] - inter);   // exact reference op order
            if (iou > 0.5f) {
                int p = atomicAdd(&npair, 1);
                if (p < PCAP) pairs[p] = ((u32)i << 10) | (u32)j;
            }
        }
    }
    __syncthreads();

    int P = npair; if (P > PCAP) P = PCAP;
    if (tid < P) {                      // rank-sort ascending; keys unique
        u32 k = pairs[tid];
        int rr = 0;
        for (int q = 0; q < P; ++q) rr += (pairs[q] < k);
        sorted[rr] = k;
    }
    __syncthreads();

    // greedy walk over sorted pairs; wave 0, lane l<16 owns sup word l
    if (wid == 0) {
        u64 sup = 0;
        for (int p = 0; p < P; ++p) {
            u32 k = sorted[p];
            int i = k >> 10;
            u64 supw = __shfl(sup, i >> 6);
            if (((supw >> (i & 63)) & 1ull) == 0ull) {   // i kept -> suppress j
                int j = (int)(k & 1023u);
                if (lane == (j >> 6)) sup |= 1ull << (j & 63);
            }
        }
        if (lane < 16) keepw[lane] = ~sup;
    }
    __syncthreads();

    float s0 = sscore[0];   // index 0 never suppressed; scores descending

    for (int i = tid; i < KTOP; i += 1024) {
        bool kp = (keepw[i >> 6] >> (i & 63)) & 1ull;
        if (kp && sscore[i] >= REL1 * s0) atomicMin(&firstIdx[scls[i] & 127], i);
    }
    __syncthreads();

    bool fin = false;
    if (tid < KTOP) {
        bool kp = (keepw[tid >> 6] >> (tid & 63)) & 1ull;
        bool v3 = kp && (sscore[tid] >= REL1 * s0);
        if (v3) {
            int f = firstIdx[scls[tid] & 127];
            bool del = (f < tid) && (sscore[tid] < REL2 * sscore[f]);
            fin = !del;
        }
    }
    u64 m = __ballot(fin);
    if (lane == 0) wtot[wid] = __popcll(m);
    __syncthreads();
    int prefix = 0, V = 0;
    for (int k = 0; k < 16; ++k) { int c = wtot[k]; if (k < wid) prefix += c; V += c; }
    int rank = prefix + __popcll(m & ((1ull << lane) - 1ull));

    float* ob = out;                          // boxes  [B,100,4]
    float* oc = out + (size_t)B * 400;        // classes[B,100] (as float)
    float* os = out + (size_t)B * 500;        // scores [B,100]
    if (fin && rank < 100) {
        int o = b * 100 + rank;
        float4 bx = sbox[tid];
        ob[o * 4 + 0] = bx.x;
        ob[o * 4 + 1] = bx.y;
        ob[o * 4 + 2] = bx.z;
        ob[o * 4 + 3] = bx.w;
        oc[o] = (float)scls[tid];
        os[o] = sscore[tid];
    }
    int Vc = V < 100 ? V : 100;
    if (tid >= Vc && tid < 100) {
        int o = b * 100 + tid;
        ob[o * 4 + 0] = 0.f;
        ob[o * 4 + 1] = 0.f;
        ob[o * 4 + 2] = 0.f;
        ob[o * 4 + 3] = 0.f;
        oc[o] = -1.f;
        os[o] = 0.f;
    }
}

extern "C" void kernel_launch(void* const* d_in, const int* in_sizes, int n_in,
                              void* d_out, int out_size, void* d_ws, size_t ws_size,
                              hipStream_t stream) {
    (void)n_in; (void)ws_size;
    float* out = (float*)d_out;
    int B = out_size / 600;          // 100*(4+1+1) per image

    // identify boxes input purely from sizes (4N vs N); robust to any permutation
    int ib = 0;
    for (int i = 1; i < 3; ++i) if (in_sizes[i] > in_sizes[ib]) ib = i;
    int o1 = -1, o2 = -1;
    for (int i = 0; i < 3; ++i) if (i != ib) { if (o1 < 0) o1 = i; else o2 = i; }
    int N = in_sizes[o1] / B;
    const float4* boxes = (const float4*)d_in[ib];
    const void* pA = d_in[o1];
    const void* pB = d_in[o2];

    char* ws = (char*)d_ws;
    size_t off = 0;
    auto alloc = [&](size_t bytes) { size_t r = off; off += (bytes + 255) & ~(size_t)255; return r; };
    size_t ph_off   = alloc((size_t)B * HB * NB * 4);     // 2 MB
    size_t bs_off   = alloc((size_t)B * NB * 4);          // gbs
    size_t be_off   = alloc((size_t)B * NB * 4);          // gbe
    size_t cnt_off  = alloc((size_t)B * 4);
    size_t kk_off   = alloc((size_t)B * CAP * 8);         // ckey
    size_t xb_off   = alloc((size_t)B * CAP * 16);        // cbox
    size_t lb_off   = alloc((size_t)B * CAP * 4);         // ccls

    int* phist  = (int*)(ws + ph_off);
    int* gbs    = (int*)(ws + bs_off);
    int* gbe    = (int*)(ws + be_off);
    int* cnt    = (int*)(ws + cnt_off);
    u64* ckey   = (u64*)(ws + kk_off);
    float4* cbox = (float4*)(ws + xb_off);
    int* ccls   = (int*)(ws + lb_off);

    hist_kernel<<<dim3(HB, B), 1024, 0, stream>>>(pA, pB, N, phist);
    collect_kernel<<<dim3(HB, B), 1024, 0, stream>>>(pA, pB, boxes, N, phist,
                                                     gbs, gbe, cnt, ckey, cbox, ccls);
    finish_kernel<<<B, 1024, 0, stream>>>(cnt, ckey, cbox, ccls, gbs, gbe, out, B);
}